// Round 3
// baseline (126241.968 us; speedup 1.0000x reference)
//
#include <hip/hip_runtime.h>
#include <cstdint>
#include <cstddef>

#define HS 512

constexpr int TPB  = 512;            // 8 waves/block
constexpr int GBLK = 64;
constexpr int OWNB = 24;             // owned carry rows per block (groups 0..23)
constexpr int WPAD = 520;            // LDS row stride for u-rows
constexpr int PW   = 1360;           // pub record width per block (floats)
// pub slots per block: [0,24) h' ; [24,127) big logit partials (100 rp + 3 wp);
// [128,228) awa partials; [228,328) awm partials; [328,840) ca partials; [840,1352) cm

// ---------------- workspace layout (float offsets) ----------------
constexpr size_t OFF_TWh0  = 0;                        // W_rh[512:1024)^T   (h)
constexpr size_t OFF_TWh1  = OFF_TWh0  + 512*512;      // W_rha[2560:3072)^T (ha)
constexpr size_t OFF_TWh2  = OFF_TWh1  + 512*512;      // W_rhm[2560:3072)^T (hm)
constexpr size_t OFF_TWu0  = OFF_TWh2  + 512*512;      // W_rh[0:512)^T      (r)
constexpr size_t OFF_TWu1  = OFF_TWu0  + 512*512;      // W_rha[2048:2560)^T
constexpr size_t OFF_TWu2  = OFF_TWu1  + 512*512;      // W_rhm[2048:2560)^T
constexpr size_t OFF_PAca  = OFF_TWu2  + 512*512;      // [4096][512]
constexpr size_t OFF_PMcm  = OFF_PAca  + 4096*512;
constexpr size_t OFF_PArha = OFF_PMcm  + 4096*512;
constexpr size_t OFF_PMrhm = OFF_PArha + 4096*512;
constexpr size_t OFF_PAwpa = OFF_PMrhm + 4096*512;     // [4096][100]
constexpr size_t OFF_PMwpm = OFF_PAwpa + 4096*100;
constexpr size_t OFF_PUB   = OFF_PMwpm + 4096*100;     // float[2][64][PW]
constexpr size_t OFF_TAG   = OFF_PUB   + 2*64*PW;      // u32[2][64*16] (64B-spread tags)

// ---------------- device helpers ----------------
__device__ __forceinline__ float aldf(const float* p) {
  return __hip_atomic_load(const_cast<float*>(p),
                           __ATOMIC_RELAXED, __HIP_MEMORY_SCOPE_AGENT);
}
__device__ __forceinline__ unsigned aldu(const unsigned* p) {
  return __hip_atomic_load(const_cast<unsigned*>(p),
                           __ATOMIC_RELAXED, __HIP_MEMORY_SCOPE_AGENT);
}
__device__ __forceinline__ void astf(float* p, float v) {
  __hip_atomic_store(p, v, __ATOMIC_RELAXED, __HIP_MEMORY_SCOPE_AGENT);
}
__device__ __forceinline__ void astu(unsigned* p, unsigned v) {
  __hip_atomic_store(p, v, __ATOMIC_RELAXED, __HIP_MEMORY_SCOPE_AGENT);
}
__device__ __forceinline__ float rsum16(float v) {
  #pragma unroll
  for (int o = 8; o; o >>= 1) v += __shfl_xor(v, o, 64);
  return v;
}

// 16-lane 512-dot: lane gl covers float4 slots gl, gl+16, ..., gl+112
__device__ __forceinline__ float dot16_512(const float* __restrict__ w,
                                           const float* x, int gl) {
  const float4* w4 = (const float4*)w;
  const float4* x4 = (const float4*)x;
  float acc = 0.f;
  #pragma unroll
  for (int it = 0; it < 8; ++it) {
    float4 a = w4[gl + 16*it];
    float4 b = x4[gl + 16*it];
    acc += a.x*b.x + a.y*b.y + a.z*b.z + a.w*b.w;
  }
  return acc;
}

__device__ __forceinline__ void dot16_2x512(const float* __restrict__ w,
                                            const float* xa, const float* xm,
                                            int gl, float& ra, float& rm) {
  const float4* w4 = (const float4*)w;
  const float4* a4 = (const float4*)xa;
  const float4* m4 = (const float4*)xm;
  float sa = 0.f, sm = 0.f;
  #pragma unroll
  for (int it = 0; it < 8; ++it) {
    float4 wv = w4[gl + 16*it], av = a4[gl + 16*it], mv = m4[gl + 16*it];
    sa += wv.x*av.x + wv.y*av.y + wv.z*av.z + wv.w*av.w;
    sm += wv.x*mv.x + wv.y*mv.y + wv.z*mv.z + wv.w*mv.w;
  }
  #pragma unroll
  for (int o = 8; o; o >>= 1) { sa += __shfl_xor(sa, o, 64); sm += __shfl_xor(sm, o, 64); }
  ra = sa; rm = sm;
}

// wave-wide softmax over src[0..99] -> dst[0..99] (pads untouched)
__device__ __forceinline__ void wsm100(const float* src, float* dst, int lane) {
  bool two = lane < 36;
  float x1 = src[lane];
  float x2 = two ? src[64 + lane] : -3.0e38f;
  float m = fmaxf(x1, x2);
  #pragma unroll
  for (int o = 32; o; o >>= 1) m = fmaxf(m, __shfl_xor(m, o, 64));
  float e1 = expf(x1 - m);
  float e2 = two ? expf(x2 - m) : 0.f;
  float ss = e1 + e2;
  #pragma unroll
  for (int o = 32; o; o >>= 1) ss += __shfl_xor(ss, o, 64);
  float inv = 1.f / ss;
  dst[lane] = e1 * inv;
  if (two) dst[64 + lane] = e2 * inv;
}

// ---------------- prep kernels ----------------
__global__ void initK(float* pub, unsigned* tag) {
  int i = blockIdx.x * blockDim.x + threadIdx.x, st = gridDim.x * blockDim.x;
  for (int k = i; k < 2 * 64 * PW; k += st) pub[k] = 0.f;
  for (int k = i; k < 2 * 1024; k += st)
    tag[k] = (k < 1024 && (k & 15) == 0) ? 1u : 0u;   // parity-0 ready (step-0 data = zeros)
}

__global__ void transK(const float* __restrict__ src, float* __restrict__ dst, int R, int C) {
  __shared__ float tile[32][33];
  int c0 = blockIdx.x * 32, r0 = blockIdx.y * 32;
  for (int i = threadIdx.y; i < 32; i += 8) {
    int r = r0 + i, c = c0 + threadIdx.x;
    tile[i][threadIdx.x] = (r < R && c < C) ? src[(size_t)r * C + c] : 0.f;
  }
  __syncthreads();
  for (int i = threadIdx.y; i < 32; i += 8) {
    int c = c0 + i, r = r0 + threadIdx.x;
    if (c < C && r < R) dst[(size_t)c * R + r] = tile[threadIdx.x][i];
  }
}

__global__ __launch_bounds__(256) void gemmK(const float* __restrict__ X,
                                             const float* __restrict__ W,
                                             float* __restrict__ C, int N) {
  __shared__ float As[16][68];
  __shared__ float Bs[16][68];
  int t0 = blockIdx.y * 64, n0 = blockIdx.x * 64;
  int tid = threadIdx.x, tx = tid & 15, ty = tid >> 4;
  float acc[4][4] = {};
  for (int k0 = 0; k0 < 2048; k0 += 16) {
    {
      int r = tid >> 2, c = (tid & 3) * 4;
      float4 v = *(const float4*)(X + (size_t)(t0 + r) * 2048 + k0 + c);
      As[c + 0][r] = v.x; As[c + 1][r] = v.y; As[c + 2][r] = v.z; As[c + 3][r] = v.w;
    }
    {
      int kr = tid >> 4, c = (tid & 15) * 4;
      int gcol = n0 + c;
      const float* src = W + (size_t)(k0 + kr) * N + gcol;
      #pragma unroll
      for (int i = 0; i < 4; ++i) Bs[kr][c + i] = (gcol + i < N) ? src[i] : 0.f;
    }
    __syncthreads();
    #pragma unroll
    for (int kk = 0; kk < 16; ++kk) {
      float4 a4 = *(const float4*)&As[kk][ty * 4];
      float4 b4 = *(const float4*)&Bs[kk][tx * 4];
      float av[4] = {a4.x, a4.y, a4.z, a4.w};
      float bv[4] = {b4.x, b4.y, b4.z, b4.w};
      #pragma unroll
      for (int i = 0; i < 4; ++i)
        #pragma unroll
        for (int j = 0; j < 4; ++j) acc[i][j] += av[i] * bv[j];
    }
    __syncthreads();
  }
  #pragma unroll
  for (int i = 0; i < 4; ++i)
    #pragma unroll
    for (int j = 0; j < 4; ++j) {
      int col = n0 + tx * 4 + j;
      if (col < N) C[(size_t)(t0 + ty * 4 + i) * N + col] = acc[i][j];
    }
}

__global__ __launch_bounds__(256) void gemm128(const float* __restrict__ X,
                                               const float* __restrict__ W,
                                               float* __restrict__ C) {
  __shared__ float As[8][132];
  __shared__ float Bs[8][132];
  const int N = 512;
  int t0 = blockIdx.y * 128, n0 = blockIdx.x * 128;
  int tid = threadIdx.x, tx = tid & 15, ty = tid >> 4;
  float acc[8][8] = {};
  for (int k0 = 0; k0 < 2048; k0 += 8) {
    int r = tid >> 1, c4 = (tid & 1) * 4;
    float4 va = *(const float4*)(X + (size_t)(t0 + r) * 2048 + k0 + c4);
    int kr = tid >> 5, cb = (tid & 31) * 4;
    float4 vb = *(const float4*)(W + (size_t)(k0 + kr) * N + n0 + cb);
    __syncthreads();
    As[c4 + 0][r] = va.x; As[c4 + 1][r] = va.y; As[c4 + 2][r] = va.z; As[c4 + 3][r] = va.w;
    Bs[kr][cb] = vb.x; Bs[kr][cb + 1] = vb.y; Bs[kr][cb + 2] = vb.z; Bs[kr][cb + 3] = vb.w;
    __syncthreads();
    #pragma unroll
    for (int kk = 0; kk < 8; ++kk) {
      float av[8], bv[8];
      *(float4*)av       = *(const float4*)&As[kk][ty * 8];
      *(float4*)(av + 4) = *(const float4*)&As[kk][ty * 8 + 4];
      *(float4*)bv       = *(const float4*)&Bs[kk][tx * 8];
      *(float4*)(bv + 4) = *(const float4*)&Bs[kk][tx * 8 + 4];
      #pragma unroll
      for (int i = 0; i < 8; ++i)
        #pragma unroll
        for (int j = 0; j < 8; ++j) acc[i][j] += av[i] * bv[j];
    }
  }
  #pragma unroll
  for (int i = 0; i < 8; ++i) {
    float* dst = C + (size_t)(t0 + ty * 8 + i) * N + n0 + tx * 8;
    *(float4*)dst       = *(float4*)&acc[i][0];
    *(float4*)(dst + 4) = *(float4*)&acc[i][4];
  }
}

// ---------------- persistent recurrence kernel ----------------
struct RArgs {
  const float *Wrp, *Wwp, *Wwpa, *Wwpm, *Wca, *Wcm;   // raw weights (row-major)
  const float *TWh0, *TWh1, *TWh2, *TWu0, *TWu1, *TWu2;
  const float *PAca, *PMcm, *PArha, *PMrhm, *PAwpa, *PMwpm;
  const float *b_ca, *b_cm, *b_wp, *b_wpa, *b_wpm, *b_rp, *b_rh, *b_rha, *b_rhm;
  float *pub;
  unsigned *tag;
  float *out;
  int nT;
};

__global__ __launch_bounds__(TPB, 1) void recurK(RArgs a) {
  const int tid  = threadIdx.x;
  const int lane = tid & 63;
  const int lw   = tid >> 6;                 // wave 0..7
  const int g    = tid >> 4;                 // 16-lane group 0..31
  const int gl   = tid & 15;
  const int b    = blockIdx.x;

  // ---- LDS (~139 KB; gfx950 allows 160 KB/WG) ----
  __shared__ __align__(16) float s_TWu[OWNB * WPAD]; // owned u-rows         49.9KB
  __shared__ __align__(16) float s_Lc[OWNB * 512];   // raw Wca/Wcm rows     49.2KB
  __shared__ __align__(16) float s_Lbig[OWNB * 104]; // raw Wrp(+Wwp) rows   10.0KB
  __shared__ __align__(16) float s_Lsm[OWNB * 104];  // raw Wwpa/Wwpm rows   10.0KB
  __shared__ __align__(16) float s_G[OWNB * 112];    // block-private G      10.8KB
  __shared__ __align__(16) float s_x[1536];          // carry [ha|hm|h]
  __shared__ __align__(16) float s_c[1024];          // [ca|cm]
  __shared__ float s_big[104], s_la[104], s_lm[104];
  __shared__ float s_ar[112], s_awa[112], s_awm[112], s_aw[4];
  __shared__ float s_hnew[OWNB];

  const bool hasHA = (b >= 21 && b <= 42);
  const bool hasHM = (b >= 42);
  unsigned maskHA = 0, maskHM = 0;
  for (int r = 0; r < OWNB; ++r) {
    int q = b * OWNB + r;
    if (q >= 512 && q < 1024) maskHA |= 1u << r;
    if (q >= 1024)            maskHM |= 1u << r;
  }

  // ---- stage LDS (once) ----
  for (int i = tid; i < OWNB * WPAD; i += TPB) {
    int rr = i / WPAD, col = i - rr * WPAD;
    if (col < 512) {
      int q = b * OWNB + rr;
      const float* src = (q < 512)  ? a.TWu0 + (size_t)q * 512
                       : (q < 1024) ? a.TWu1 + (size_t)(q - 512) * 512
                                    : a.TWu2 + (size_t)(q - 1024) * 512;
      s_TWu[i] = src[col];
    }
  }
  for (int i = tid; i < OWNB * 512; i += TPB) {
    int rr = i >> 9, col = i & 511;
    int q = b * OWNB + rr;
    float v = 0.f;
    if (q >= 512 && q < 1024) v = a.Wca[(size_t)(q - 512) * 512 + col];
    else if (q >= 1024)       v = a.Wcm[(size_t)(q - 1024) * 512 + col];
    s_Lc[i] = v;
  }
  for (int i = tid; i < OWNB * 104; i += TPB) {
    int rr = i / 104, k = i - rr * 104;
    int q = b * OWNB + rr;
    int xr = (q < 512) ? 1024 + q : q - 512;     // q-space -> xh-row
    float v = 0.f;
    if (k < 100)      v = a.Wrp[(size_t)xr * 100 + k];
    else if (k < 103) v = a.Wwp[(size_t)xr * 3 + (k - 100)];
    s_Lbig[i] = v;
  }
  for (int i = tid; i < OWNB * 104; i += TPB) {
    int rr = i / 104, k = i - rr * 104;
    int q = b * OWNB + rr;
    float v = 0.f;
    if (k < 100) {
      if (q >= 512 && q < 1024) v = a.Wwpa[(size_t)(q - 512) * 100 + k];
      else if (q >= 1024)       v = a.Wwpm[(size_t)(q - 1024) * 100 + k];
    }
    s_Lsm[i] = v;
  }
  for (int i = tid; i < OWNB * 112; i += TPB) s_G[i] = 0.f;
  if (tid < 112) { s_ar[tid] = 0.f; s_awa[tid] = 0.f; s_awm[tid] = 0.f; }

  // ---- per-thread constants ----
  const float bCa = a.b_ca[tid];
  const float bCm = a.b_cm[tid];

  // gather-sum role
  int sKind = -1, sIdx = 0;
  float sBias = 0.f;
  const float* sPre = nullptr;
  if (tid < 103) { sKind = 0; sIdx = tid;
    sBias = (tid < 100) ? a.b_rp[tid] : a.b_wp[tid - 100]; }
  else if (tid >= 104 && tid < 204) { sKind = 1; sIdx = tid - 104;
    sBias = a.b_wpa[sIdx]; sPre = a.PAwpa + sIdx; }
  else if (tid >= 204 && tid < 304) { sKind = 2; sIdx = tid - 204;
    sBias = a.b_wpm[sIdx]; sPre = a.PMwpm + sIdx; }

  // owner role: groups 0..23
  const bool own = (g < OWNB);
  int typeO = 0, jO = 0, whXo = 0;
  float biasO = 0.f;
  const float* preOPtr = nullptr;
  const float* whPtr = nullptr;
  if (own) {
    int q = b * OWNB + g;
    if (q < 512)       { typeO = 0; jO = q;        biasO = a.b_rh[jO];
                         whPtr = a.TWh0 + (size_t)jO * 512; whXo = 1024; }
    else if (q < 1024) { typeO = 1; jO = q - 512;  biasO = a.b_rha[jO];
                         preOPtr = a.PArha + jO;
                         whPtr = a.TWh1 + (size_t)jO * 512; whXo = 0; }
    else               { typeO = 2; jO = q - 1024; biasO = a.b_rhm[jO];
                         preOPtr = a.PMrhm + jO;
                         whPtr = a.TWh2 + (size_t)jO * 512; whXo = 512; }
  }

  // x-gather map: thread covers q = tid, tid+512, tid+1024
  int xsrc[3], xdst[3];
  #pragma unroll
  for (int s = 0; s < 3; ++s) {
    int q = tid + s * 512;
    xsrc[s] = (q / 24) * PW + (q % 24);
    xdst[s] = (q < 512) ? 1024 + q : q - 512;
  }
  __syncthreads();

  // ---------------- time loop: ONE global exchange per step ----------------
  for (int t = 0; t < a.nT; ++t) {
    const unsigned tagB = (unsigned)t + 1;
    const int par = t & 1;
    const float* pb = a.pub + (size_t)par * (64 * PW);
    float* po = a.pub + (size_t)((t + 1) & 1) * (64 * PW) + (size_t)b * PW;

    // per-step prefetch (normal cached loads; land during poll)
    float preCa = a.PAca[(size_t)t * 512 + tid];
    float preCm = a.PMcm[(size_t)t * 512 + tid];
    float preS  = sPre ? sPre[(size_t)t * 100] : 0.f;
    float preO  = preOPtr ? preOPtr[(size_t)t * 512] : 0.f;

    // ---- poll: every wave independently (no barrier; 64B-spread tags) ----
    {
      const unsigned* tp = a.tag + (size_t)par * 1024;
      for (;;) {
        unsigned v = aldu(tp + lane * 16);
        if (__all((int)(v >= tagB))) break;
        __builtin_amdgcn_s_sleep(1);
      }
    }

    // ---- bulk gather + partial sums (all local after this) ----
    {
      float xv0 = aldf(pb + xsrc[0]);
      float xv1 = aldf(pb + xsrc[1]);
      float xv2 = aldf(pb + xsrc[2]);
      s_x[xdst[0]] = xv0; s_x[xdst[1]] = xv1; s_x[xdst[2]] = xv2;
    }
    {
      float accA = 0.f, accM = 0.f;
      #pragma unroll
      for (int p = 21; p <= 42; ++p) accA += aldf(pb + p * PW + 328 + tid);
      #pragma unroll
      for (int p = 42; p <= 63; ++p) accM += aldf(pb + p * PW + 840 + tid);
      s_c[tid]       = fmaxf(accA + preCa + bCa, 0.f);
      s_c[512 + tid] = fmaxf(accM + preCm + bCm, 0.f);
    }
    if (sKind == 0) {
      float acc = 0.f;
      #pragma unroll 16
      for (int p = 0; p < 64; ++p) acc += aldf(pb + p * PW + 24 + sIdx);
      s_big[sIdx] = acc + sBias;
    } else if (sKind == 1) {
      float acc = 0.f;
      #pragma unroll
      for (int p = 21; p <= 42; ++p) acc += aldf(pb + p * PW + 128 + sIdx);
      s_la[sIdx] = acc + sBias + preS;
    } else if (sKind == 2) {
      float acc = 0.f;
      #pragma unroll
      for (int p = 42; p <= 63; ++p) acc += aldf(pb + p * PW + 228 + sIdx);
      s_lm[sIdx] = acc + sBias + preS;
    }
    __syncthreads();   // B1: s_x/s_c/logits ready

    // ---- wh dots (owners, from L2) in parallel with softmax (waves 6,7) ----
    float whv = 0.f;
    if (own) whv = rsum16(dot16_512(whPtr, s_x + whXo, gl));
    if (lw == 6) {
      wsm100(s_big, s_ar, lane);
      wsm100(s_lm, s_awm, lane);
    } else if (lw == 7) {
      wsm100(s_la, s_awa, lane);
      float z = (lane < 3) ? s_big[100 + lane] : -3.0e38f;
      float m = z;
      #pragma unroll
      for (int o = 32; o; o >>= 1) m = fmaxf(m, __shfl_xor(m, o, 64));
      float e = (lane < 3) ? expf(z - m) : 0.f;
      float ss = e;
      #pragma unroll
      for (int o = 32; o; o >>= 1) ss += __shfl_xor(ss, o, 64);
      if (lane < 3) s_aw[lane] = e / ss;
    }
    __syncthreads();   // B2: softmaxes ready

    // ---- owned phase: u-dots + contrib + h' publish ----
    float aw0 = 0.f, aw1 = 0.f, aw2 = 0.f, uA = 0.f, uM = 0.f;
    float gv[7];
    if (own) {
      aw0 = s_aw[0]; aw1 = s_aw[1]; aw2 = s_aw[2];
      dot16_2x512(s_TWu + (size_t)g * WPAD, s_c, s_c + 512, gl, uA, uM);
      float* grow = s_G + g * 112;
      float contrib = 0.f;
      #pragma unroll
      for (int k = 0; k < 7; ++k) {
        int idx = gl + 16 * k;           // pads 100..111 hold zeros
        gv[k] = grow[idx];
        contrib += s_ar[idx] * gv[k];
      }
      contrib = rsum16(contrib);
      if (!gl) {
        float h = fmaxf(contrib + whv + preO + biasO, 0.f);
        if (typeO == 0) a.out[(size_t)t * 512 + jO] = h;
        astf(po + g, h);
        s_hnew[g] = h;
      }
    }
    __syncthreads();   // B3: s_hnew ready

    // ---- partial publish: contributions of own 24 h' to next step's logits/c ----
    if (tid < 103) {
      float acc = 0.f;
      #pragma unroll
      for (int r = 0; r < OWNB; ++r) acc += s_hnew[r] * s_Lbig[r * 104 + tid];
      astf(po + 24 + tid, acc);
    } else if (tid >= 104 && tid < 204) {
      if (hasHA) {
        int kk = tid - 104;
        float acc = 0.f;
        #pragma unroll
        for (int r = 0; r < OWNB; ++r)
          if (maskHA >> r & 1) acc += s_hnew[r] * s_Lsm[r * 104 + kk];
        astf(po + 128 + kk, acc);
      }
    } else if (tid >= 204 && tid < 304) {
      if (hasHM) {
        int kk = tid - 204;
        float acc = 0.f;
        #pragma unroll
        for (int r = 0; r < OWNB; ++r)
          if (maskHM >> r & 1) acc += s_hnew[r] * s_Lsm[r * 104 + kk];
        astf(po + 228 + kk, acc);
      }
    }
    if (hasHA | hasHM) {
      float accA = 0.f, accM = 0.f;
      #pragma unroll
      for (int r = 0; r < OWNB; ++r) {
        float v = s_hnew[r] * s_Lc[r * 512 + tid];
        if (maskHA >> r & 1) accA += v;
        if (maskHM >> r & 1) accM += v;
      }
      if (hasHA) astf(po + 328 + tid, accA);
      if (hasHM) astf(po + 840 + tid, accM);
    }
    asm volatile("s_waitcnt vmcnt(0)" ::: "memory");
    __syncthreads();   // B4: all publishes drained
    if (tid == 0) astu(a.tag + (size_t)((t + 1) & 1) * 1024 + b * 16, tagB + 1);

    // ---- G update (off the inter-block critical path) ----
    if (own) {
      float* grow = s_G + g * 112;
      #pragma unroll
      for (int k = 0; k < 7; ++k) {
        int idx = gl + 16 * k;
        grow[idx] = aw0 * gv[k] + aw1 * s_awa[idx] * uA + aw2 * s_awm[idx] * uM;
      }
    }
  }
}

// ---------------- host ----------------
extern "C" void kernel_launch(void* const* d_in, const int* in_sizes, int n_in,
                              void* d_out, int out_size, void* d_ws, size_t ws_size,
                              hipStream_t stream) {
  const float* Xa    = (const float*)d_in[0];
  const float* Xm    = (const float*)d_in[1];
  const float* W_ca  = (const float*)d_in[2];  const float* b_ca  = (const float*)d_in[3];
  const float* W_cm  = (const float*)d_in[4];  const float* b_cm  = (const float*)d_in[5];
  const float* W_wp  = (const float*)d_in[6];  const float* b_wp  = (const float*)d_in[7];
  const float* W_wpa = (const float*)d_in[8];  const float* b_wpa = (const float*)d_in[9];
  const float* W_wpm = (const float*)d_in[10]; const float* b_wpm = (const float*)d_in[11];
  const float* W_rp  = (const float*)d_in[12]; const float* b_rp  = (const float*)d_in[13];
  const float* W_rh  = (const float*)d_in[14]; const float* b_rh  = (const float*)d_in[15];
  const float* W_rha = (const float*)d_in[16]; const float* b_rha = (const float*)d_in[17];
  const float* W_rhm = (const float*)d_in[18]; const float* b_rhm = (const float*)d_in[19];

  int nT = out_size / HS;   // 4096
  float* ws = (float*)d_ws;

  initK<<<dim3(64), dim3(256), 0, stream>>>(ws + OFF_PUB, (unsigned*)(ws + OFF_TAG));

  dim3 tb(32, 8);
  auto tg = [](int R, int C) { return dim3((C + 31) / 32, (R + 31) / 32); };
  transK<<<tg(512, 512), tb, 0, stream>>>(W_rh  + 512 * 512,          ws + OFF_TWh0, 512, 512);
  transK<<<tg(512, 512), tb, 0, stream>>>(W_rha + (size_t)2560 * 512, ws + OFF_TWh1, 512, 512);
  transK<<<tg(512, 512), tb, 0, stream>>>(W_rhm + (size_t)2560 * 512, ws + OFF_TWh2, 512, 512);
  transK<<<tg(512, 512), tb, 0, stream>>>(W_rh,                       ws + OFF_TWu0, 512, 512);
  transK<<<tg(512, 512), tb, 0, stream>>>(W_rha + (size_t)2048 * 512, ws + OFF_TWu1, 512, 512);
  transK<<<tg(512, 512), tb, 0, stream>>>(W_rhm + (size_t)2048 * 512, ws + OFF_TWu2, 512, 512);

  int tB = nT / 128;
  gemm128<<<dim3(4, tB), dim3(256), 0, stream>>>(Xa, W_ca + (size_t)512 * 512, ws + OFF_PAca);
  gemm128<<<dim3(4, tB), dim3(256), 0, stream>>>(Xm, W_cm + (size_t)512 * 512, ws + OFF_PMcm);
  gemm128<<<dim3(4, tB), dim3(256), 0, stream>>>(Xa, W_rha,                    ws + OFF_PArha);
  gemm128<<<dim3(4, tB), dim3(256), 0, stream>>>(Xm, W_rhm,                    ws + OFF_PMrhm);
  int tB64 = nT / 64;
  gemmK<<<dim3(2, tB64), dim3(256), 0, stream>>>(Xa, W_wpa + (size_t)512 * 100, ws + OFF_PAwpa, 100);
  gemmK<<<dim3(2, tB64), dim3(256), 0, stream>>>(Xm, W_wpm + (size_t)512 * 100, ws + OFF_PMwpm, 100);

  RArgs a;
  a.Wrp = W_rp; a.Wwp = W_wp; a.Wwpa = W_wpa; a.Wwpm = W_wpm; a.Wca = W_ca; a.Wcm = W_cm;
  a.TWh0 = ws + OFF_TWh0; a.TWh1 = ws + OFF_TWh1; a.TWh2 = ws + OFF_TWh2;
  a.TWu0 = ws + OFF_TWu0; a.TWu1 = ws + OFF_TWu1; a.TWu2 = ws + OFF_TWu2;
  a.PAca = ws + OFF_PAca; a.PMcm = ws + OFF_PMcm;
  a.PArha = ws + OFF_PArha; a.PMrhm = ws + OFF_PMrhm;
  a.PAwpa = ws + OFF_PAwpa; a.PMwpm = ws + OFF_PMwpm;
  a.b_ca = b_ca; a.b_cm = b_cm; a.b_wp = b_wp; a.b_wpa = b_wpa; a.b_wpm = b_wpm;
  a.b_rp = b_rp; a.b_rh = b_rh; a.b_rha = b_rha; a.b_rhm = b_rhm;
  a.pub = ws + OFF_PUB;
  a.tag = (unsigned*)(ws + OFF_TAG);
  a.out = (float*)d_out;
  a.nT  = nT;

  recurK<<<dim3(GBLK), dim3(TPB), 0, stream>>>(a);
}

// Round 4
// 26970.023 us; speedup vs baseline: 4.6808x; 4.6808x over previous
//
#include <hip/hip_runtime.h>
#include <cstdint>
#include <cstddef>

#define HS 512

constexpr int TPB  = 512;            // 8 waves/block
constexpr int GBLK = 64;
constexpr int OWNB = 24;             // owned carry rows per block (one per 16-lane group)
constexpr int OWNW = 3;              // (unused; kept for layout parity)
constexpr int WPAD = 516;            // padded LDS row stride (floats)

// ---------------- workspace layout (float offsets) ----------------
constexpr size_t OFF_TWrp  = 0;                       // [100][1536]
constexpr size_t OFF_TWwp  = OFF_TWrp  + 100*1536;    // [3][1536]
constexpr size_t OFF_TWwpa = OFF_TWwp  + 3*1536;      // [100][512]
constexpr size_t OFF_TWwpm = OFF_TWwpa + 100*512;
constexpr size_t OFF_TWca  = OFF_TWwpm + 100*512;     // [512][512]
constexpr size_t OFF_TWcm  = OFF_TWca  + 512*512;
constexpr size_t OFF_TWh0  = OFF_TWcm  + 512*512;     // W_rh[512:1024)^T   (h)
constexpr size_t OFF_TWh1  = OFF_TWh0  + 512*512;     // W_rha[2560:3072)^T (ha)
constexpr size_t OFF_TWh2  = OFF_TWh1  + 512*512;     // W_rhm[2560:3072)^T (hm)
constexpr size_t OFF_TWu0  = OFF_TWh2  + 512*512;     // W_rh[0:512)^T      (r)
constexpr size_t OFF_TWu1  = OFF_TWu0  + 512*512;     // W_rha[2048:2560)^T
constexpr size_t OFF_TWu2  = OFF_TWu1  + 512*512;     // W_rhm[2048:2560)^T
constexpr size_t OFF_PAca  = OFF_TWu2  + 512*512;     // [4096][512]
constexpr size_t OFF_PMcm  = OFF_PAca  + 4096*512;
constexpr size_t OFF_PArha = OFF_PMcm  + 4096*512;
constexpr size_t OFF_PMrhm = OFF_PArha + 4096*512;
constexpr size_t OFF_PAwpa = OFF_PMrhm + 4096*512;    // [4096][100]
constexpr size_t OFF_PMwpm = OFF_PAwpa + 4096*100;
constexpr size_t OFF_CARRY = OFF_PMwpm + 4096*100;    // u64[2][1536] tagged
constexpr size_t OFF_BCAST = OFF_CARRY + 2*1536*2;    // u64[2][1344] tagged
// bcast: [0:512) ca  [512:1024) cm  [1024:1124) grp  [1124:1224) gwpa
//        [1224:1324) gwpm  [1324:1327) wp

// ---------------- device helpers ----------------
__device__ __forceinline__ unsigned long long ald(const unsigned long long* p) {
  return __hip_atomic_load(const_cast<unsigned long long*>(p),
                           __ATOMIC_RELAXED, __HIP_MEMORY_SCOPE_AGENT);
}
__device__ __forceinline__ void gstTag(unsigned long long* p, float v, unsigned tag) {
  unsigned long long u = ((unsigned long long)tag << 32) | (unsigned long long)__float_as_uint(v);
  __hip_atomic_store(p, u, __ATOMIC_RELAXED, __HIP_MEMORY_SCOPE_AGENT);
}
__device__ __forceinline__ float xrsum(float v) {
  #pragma unroll
  for (int o = 32; o; o >>= 1) v += __shfl_xor(v, o, 64);
  return v;
}
__device__ __forceinline__ float rsum16(float v) {
  // xor masks < 16 keep exchange within the 16-lane group
  #pragma unroll
  for (int o = 8; o; o >>= 1) v += __shfl_xor(v, o, 64);
  return v;
}

template<int K4>
__device__ __forceinline__ float dotK(const float* __restrict__ w, const float* x) {
  int l = threadIdx.x & 63;
  const float4* w4 = (const float4*)w;
  const float4* x4 = (const float4*)x;
  float acc = 0.f;
  #pragma unroll
  for (int it = 0; it < K4; ++it) {
    float4 a = w4[l + 64*it];
    float4 b = x4[l + 64*it];
    acc += a.x*b.x + a.y*b.y + a.z*b.z + a.w*b.w;
  }
  return acc;
}

// 16-lane 512-dot: lane gl covers float4 slots gl, gl+16, ..., gl+112
__device__ __forceinline__ float dot16_512(const float* __restrict__ w,
                                           const float* x, int gl) {
  const float4* w4 = (const float4*)w;
  const float4* x4 = (const float4*)x;
  float acc = 0.f;
  #pragma unroll
  for (int it = 0; it < 8; ++it) {
    float4 a = w4[gl + 16*it];
    float4 b = x4[gl + 16*it];
    acc += a.x*b.x + a.y*b.y + a.z*b.z + a.w*b.w;
  }
  return acc;
}

// 16-lane dual 512-dot sharing the weight row (uA = w.c_a, uM = w.c_m)
__device__ __forceinline__ void dot16_2x512(const float* __restrict__ w,
                                            const float* xa, const float* xm,
                                            int gl, float& ra, float& rm) {
  const float4* w4 = (const float4*)w;
  const float4* a4 = (const float4*)xa;
  const float4* m4 = (const float4*)xm;
  float sa = 0.f, sm = 0.f;
  #pragma unroll
  for (int it = 0; it < 8; ++it) {
    float4 wv = w4[gl + 16*it], av = a4[gl + 16*it], mv = m4[gl + 16*it];
    sa += wv.x*av.x + wv.y*av.y + wv.z*av.z + wv.w*av.w;
    sm += wv.x*mv.x + wv.y*mv.y + wv.z*mv.z + wv.w*mv.w;
  }
  #pragma unroll
  for (int o = 8; o; o >>= 1) { sa += __shfl_xor(sa, o, 64); sm += __shfl_xor(sm, o, 64); }
  ra = sa; rm = sm;
}

// ---------------- prep kernels ----------------
__global__ void initK(unsigned long long* carryT, unsigned long long* bcast) {
  int i = blockIdx.x * blockDim.x + threadIdx.x, st = gridDim.x * blockDim.x;
  for (int k = i; k < 1536; k += st) carryT[k] = (1ull << 32);   // carry(0)=0, tag 1
  for (int k = i; k < 1536; k += st) carryT[1536 + k] = 0ull;
  for (int k = i; k < 2 * 1344; k += st) bcast[k] = 0ull;
}

__global__ void transK(const float* __restrict__ src, float* __restrict__ dst, int R, int C) {
  __shared__ float tile[32][33];
  int c0 = blockIdx.x * 32, r0 = blockIdx.y * 32;
  for (int i = threadIdx.y; i < 32; i += 8) {
    int r = r0 + i, c = c0 + threadIdx.x;
    tile[i][threadIdx.x] = (r < R && c < C) ? src[(size_t)r * C + c] : 0.f;
  }
  __syncthreads();
  for (int i = threadIdx.y; i < 32; i += 8) {
    int c = c0 + i, r = r0 + threadIdx.x;
    if (c < C && r < R) dst[(size_t)c * R + r] = tile[threadIdx.x][i];
  }
}

__global__ __launch_bounds__(256) void gemmK(const float* __restrict__ X,
                                             const float* __restrict__ W,
                                             float* __restrict__ C, int N) {
  __shared__ float As[16][68];
  __shared__ float Bs[16][68];
  int t0 = blockIdx.y * 64, n0 = blockIdx.x * 64;
  int tid = threadIdx.x, tx = tid & 15, ty = tid >> 4;
  float acc[4][4] = {};
  for (int k0 = 0; k0 < 2048; k0 += 16) {
    {
      int r = tid >> 2, c = (tid & 3) * 4;
      float4 v = *(const float4*)(X + (size_t)(t0 + r) * 2048 + k0 + c);
      As[c + 0][r] = v.x; As[c + 1][r] = v.y; As[c + 2][r] = v.z; As[c + 3][r] = v.w;
    }
    {
      int kr = tid >> 4, c = (tid & 15) * 4;
      int gcol = n0 + c;
      const float* src = W + (size_t)(k0 + kr) * N + gcol;
      #pragma unroll
      for (int i = 0; i < 4; ++i) Bs[kr][c + i] = (gcol + i < N) ? src[i] : 0.f;
    }
    __syncthreads();
    #pragma unroll
    for (int kk = 0; kk < 16; ++kk) {
      float4 a4 = *(const float4*)&As[kk][ty * 4];
      float4 b4 = *(const float4*)&Bs[kk][tx * 4];
      float av[4] = {a4.x, a4.y, a4.z, a4.w};
      float bv[4] = {b4.x, b4.y, b4.z, b4.w};
      #pragma unroll
      for (int i = 0; i < 4; ++i)
        #pragma unroll
        for (int j = 0; j < 4; ++j) acc[i][j] += av[i] * bv[j];
    }
    __syncthreads();
  }
  #pragma unroll
  for (int i = 0; i < 4; ++i)
    #pragma unroll
    for (int j = 0; j < 4; ++j) {
      int col = n0 + tx * 4 + j;
      if (col < N) C[(size_t)(t0 + ty * 4 + i) * N + col] = acc[i][j];
    }
}

__global__ __launch_bounds__(256) void gemm128(const float* __restrict__ X,
                                               const float* __restrict__ W,
                                               float* __restrict__ C) {
  __shared__ float As[8][132];
  __shared__ float Bs[8][132];
  const int N = 512;
  int t0 = blockIdx.y * 128, n0 = blockIdx.x * 128;
  int tid = threadIdx.x, tx = tid & 15, ty = tid >> 4;
  float acc[8][8] = {};
  for (int k0 = 0; k0 < 2048; k0 += 8) {
    int r = tid >> 1, c4 = (tid & 1) * 4;
    float4 va = *(const float4*)(X + (size_t)(t0 + r) * 2048 + k0 + c4);
    int kr = tid >> 5, cb = (tid & 31) * 4;
    float4 vb = *(const float4*)(W + (size_t)(k0 + kr) * N + n0 + cb);
    __syncthreads();
    As[c4 + 0][r] = va.x; As[c4 + 1][r] = va.y; As[c4 + 2][r] = va.z; As[c4 + 3][r] = va.w;
    Bs[kr][cb] = vb.x; Bs[kr][cb + 1] = vb.y; Bs[kr][cb + 2] = vb.z; Bs[kr][cb + 3] = vb.w;
    __syncthreads();
    #pragma unroll
    for (int kk = 0; kk < 8; ++kk) {
      float av[8], bv[8];
      *(float4*)av       = *(const float4*)&As[kk][ty * 8];
      *(float4*)(av + 4) = *(const float4*)&As[kk][ty * 8 + 4];
      *(float4*)bv       = *(const float4*)&Bs[kk][tx * 8];
      *(float4*)(bv + 4) = *(const float4*)&Bs[kk][tx * 8 + 4];
      #pragma unroll
      for (int i = 0; i < 8; ++i)
        #pragma unroll
        for (int j = 0; j < 8; ++j) acc[i][j] += av[i] * bv[j];
    }
  }
  #pragma unroll
  for (int i = 0; i < 8; ++i) {
    float* dst = C + (size_t)(t0 + ty * 8 + i) * N + n0 + tx * 8;
    *(float4*)dst       = *(float4*)&acc[i][0];
    *(float4*)(dst + 4) = *(float4*)&acc[i][4];
  }
}

// ---------------- persistent recurrence kernel ----------------
struct RArgs {
  const float *TWrp, *TWwp, *TWwpa, *TWwpm, *TWca, *TWcm;
  const float *TWh0, *TWh1, *TWh2, *TWu0, *TWu1, *TWu2;
  const float *PAca, *PMcm, *PArha, *PMrhm, *PAwpa, *PMwpm;
  const float *b_ca, *b_cm, *b_wp, *b_wpa, *b_wpm, *b_rp, *b_rh, *b_rha, *b_rhm;
  unsigned long long *carryT, *bcast;
  float *out;
  int nT;
};

__global__ __launch_bounds__(TPB, 1) void recurK(RArgs a) {
  const int tid  = threadIdx.x;
  const int lane = tid & 63;
  const int lw   = tid >> 6;                 // wave 0..7
  const int g    = tid >> 4;                 // 16-lane group 0..31
  const int gl   = tid & 15;
  const int b    = blockIdx.x;

  // ---- LDS (~123 KB static; gfx950 allows 160 KB/WG) ----
  __shared__ __align__(16) float s_wca[8 * WPAD];    // ca rows (cols b*8..b*8+7)
  __shared__ __align__(16) float s_wcm[8 * WPAD];
  __shared__ __align__(16) float s_wbig[2 * 1536];   // grp / wp rows
  __shared__ __align__(16) float s_wsm[4 * WPAD];    // gwpa / gwpm rows
  __shared__ __align__(16) float s_TWu[OWNB * WPAD]; // owned u-rows
  __shared__ __align__(16) float s_G[OWNB * 112];    // block-private G (padded 112)
  __shared__ __align__(16) float s_x[1536];          // carry [ha|hm|h]
  __shared__ __align__(16) float s_c[1024];          // [ca|cm]
  __shared__ float s_ar[112], s_awa[112], s_awm[112], s_aw[4];

  // ---- static assignment maps ----
  const int r0a = (b + 51) & 63;                 // gwpa rows r0a, r0a+64(if<36)
  const int r1m = (b + 25) & 63;                 // gwpm rows
  const bool big1_grp = (b < 36);
  const bool big1_wp  = (b >= 40 && b <= 42);

  // ---- stage weights into LDS (once; pads never read as data) ----
  for (int i = tid; i < 8 * WPAD; i += TPB) {
    int row = i / WPAD, col = i - row * WPAD;
    if (col < 512) {
      s_wca[i] = a.TWca[(size_t)(b * 8 + row) * 512 + col];
      s_wcm[i] = a.TWcm[(size_t)(b * 8 + row) * 512 + col];
    }
  }
  for (int i = tid; i < 1536; i += TPB) {
    s_wbig[i] = a.TWrp[(size_t)b * 1536 + i];
    float v2 = 0.f;
    if (big1_grp)      v2 = a.TWrp[(size_t)(b + 64) * 1536 + i];
    else if (big1_wp)  v2 = a.TWwp[(size_t)(b - 40) * 1536 + i];
    s_wbig[1536 + i] = v2;
  }
  for (int i = tid; i < 4 * WPAD; i += TPB) {
    int sl = i / WPAD, col = i - sl * WPAD;
    float v = 0.f;
    if (col < 512) {
      if (sl == 0)      v = a.TWwpa[(size_t)r0a * 512 + col];
      else if (sl == 1) v = (r0a < 36) ? a.TWwpa[(size_t)(r0a + 64) * 512 + col] : 0.f;
      else if (sl == 2) v = a.TWwpm[(size_t)r1m * 512 + col];
      else              v = (r1m < 36) ? a.TWwpm[(size_t)(r1m + 64) * 512 + col] : 0.f;
    }
    s_wsm[i] = v;
  }
  for (int i = tid; i < OWNB * WPAD; i += TPB) {
    int rr = i / WPAD, col = i - rr * WPAD;
    if (col < 512) {
      int q = b * OWNB + rr, hsel = q >> 9, j = q & 511;
      const float* src = (hsel == 0) ? a.TWu0 : (hsel == 1) ? a.TWu1 : a.TWu2;
      s_TWu[i] = src[(size_t)j * 512 + col];
    }
  }
  for (int i = tid; i < OWNB * 112; i += TPB) s_G[i] = 0.f;
  if (tid < 112) { s_ar[tid] = 0.f; s_awa[tid] = 0.f; s_awm[tid] = 0.f; }

  // ---- per-thread roles ----
  // phase A group jobs: waves 0-1 = ca cols, 2-3 = cm cols, 4 = small gates,
  // 5 = none (starts wh early), 6 = big0 (grp b), 7 = big1 (grp b+64 / wp)
  int dstA = -1, xoffA = 0, strideA = 512, rowA = 0;
  float biasA = 0.f;
  const float* preAPtr = nullptr;
  if (lw < 2) {
    int col = b * 8 + g; rowA = g;
    dstA = col; biasA = a.b_ca[col]; preAPtr = a.PAca + col;
  } else if (lw < 4) {
    int col = b * 8 + (g - 8); rowA = g - 8;
    dstA = 512 + col; biasA = a.b_cm[col]; preAPtr = a.PMcm + col;
  } else if (lw == 4) {
    int sl = g - 16;
    if (sl == 0)                  { rowA = 0; dstA = 1124 + r0a;      biasA = a.b_wpa[r0a];      preAPtr = a.PAwpa + r0a;      xoffA = 0;   strideA = 100; }
    else if (sl == 1 && r0a < 36) { rowA = 1; dstA = 1124 + r0a + 64; biasA = a.b_wpa[r0a + 64]; preAPtr = a.PAwpa + r0a + 64; xoffA = 0;   strideA = 100; }
    else if (sl == 2)             { rowA = 2; dstA = 1224 + r1m;      biasA = a.b_wpm[r1m];      preAPtr = a.PMwpm + r1m;      xoffA = 512; strideA = 100; }
    else if (sl == 3 && r1m < 36) { rowA = 3; dstA = 1224 + r1m + 64; biasA = a.b_wpm[r1m + 64]; preAPtr = a.PMwpm + r1m + 64; xoffA = 512; strideA = 100; }
  }
  int dstBig = -1, bigOff = 0;
  float biasBig = 0.f;
  if (lw == 6) { dstBig = 1024 + b; biasBig = a.b_rp[b]; bigOff = 0; }
  else if (lw == 7) {
    if (big1_grp)      { dstBig = 1024 + b + 64;  biasBig = a.b_rp[b + 64]; bigOff = 1536; }
    else if (big1_wp)  { dstBig = 1324 + (b - 40); biasBig = a.b_wp[b - 40]; bigOff = 1536; }
  }
  // owned / wh: group g < 24 owns carry row q = b*24+g (wh row == owned row)
  int ownHsel = 0, ownJ = 0, whXo = 0;
  float biasO = 0.f;
  const float* preOPtr = nullptr;
  const float* whPtr = nullptr;
  if (g < OWNB) {
    int q = b * OWNB + g, hsel = q >> 9, j = q & 511;
    ownHsel = hsel; ownJ = j;
    if (hsel == 0)      { biasO = a.b_rh[j];                           whPtr = a.TWh0 + (size_t)j * 512; whXo = 1024; }
    else if (hsel == 1) { biasO = a.b_rha[j]; preOPtr = a.PArha + j;   whPtr = a.TWh1 + (size_t)j * 512; whXo = 0; }
    else                { biasO = a.b_rhm[j]; preOPtr = a.PMrhm + j;   whPtr = a.TWh2 + (size_t)j * 512; whXo = 512; }
  }
  __syncthreads();

  // ---------------- time loop ----------------
  float whv = 0.f;
  for (int t = 0; t < a.nT; ++t) {
    const unsigned tagB = (unsigned)t + 1;
    unsigned long long* bc = a.bcast + (size_t)(t & 1) * 1344;

    // prefetch per-step scalars — PIN them before the poll so the compiler
    // cannot sink the (possibly HBM-missing) loads onto the post-poll path
    float preA = preAPtr ? preAPtr[(size_t)t * strideA] : 0.f;
    float preO = preOPtr ? preOPtr[(size_t)t * 512] : 0.f;
    asm volatile("" :: "v"(preA), "v"(preO));

    // ---- poll carry(t): 3 slots/thread (hot for 2 iters, then sleep) ----
    {
      const unsigned long long* cin = a.carryT + (size_t)(t & 1) * 1536;
      int i0 = tid, i1 = tid + 512, i2 = tid + 1024;
      unsigned long long v0 = ald(cin + i0), v1 = ald(cin + i1), v2 = ald(cin + i2);
      int spin = 0;
      while (((unsigned)(v0 >> 32) < tagB) | ((unsigned)(v1 >> 32) < tagB) |
             ((unsigned)(v2 >> 32) < tagB)) {
        if (++spin > 2) __builtin_amdgcn_s_sleep(1);
        v0 = ald(cin + i0); v1 = ald(cin + i1); v2 = ald(cin + i2);
      }
      s_x[i0] = __uint_as_float((unsigned)v0);
      s_x[i1] = __uint_as_float((unsigned)v1);
      s_x[i2] = __uint_as_float((unsigned)v2);
    }
    __syncthreads();   // SYNC0

    // ---- phase A: all critical publishes in ONE parallel round ----
    if (lw < 2) {
      float v = rsum16(dot16_512(s_wca + rowA * WPAD, s_x, gl));
      if (!gl) gstTag(bc + dstA, fmaxf(v + preA + biasA, 0.f), tagB);
    } else if (lw < 4) {
      float v = rsum16(dot16_512(s_wcm + rowA * WPAD, s_x + 512, gl));
      if (!gl) gstTag(bc + dstA, fmaxf(v + preA + biasA, 0.f), tagB);
    } else if (lw == 4) {
      if (dstA >= 0) {
        float v = rsum16(dot16_512(s_wsm + rowA * WPAD, s_x + xoffA, gl));
        if (!gl) gstTag(bc + dstA, v + preA + biasA, tagB);
      }
    } else if (lw >= 6) {
      if (dstBig >= 0) {
        float v = xrsum(dotK<6>(s_wbig + bigOff, s_x));
        if (!lane) gstTag(bc + dstBig, v + biasBig, tagB);
      }
    }
    // wh dots from L2 (off the inter-block critical path); result stays in reg
    if (g < OWNB) whv = rsum16(dot16_512(whPtr, s_x + whXo, gl));

    // ---- phase B polls: waves 0-3 softmax groups, waves 4-7 gather c ----
    if (lw < 3) {
      int base = 1024 + lw * 100;       // grp / gwpa / gwpm
      const unsigned long long* p1 = bc + base + lane;
      bool two = lane < 36;
      unsigned long long v1 = ald(p1);
      unsigned long long v2 = two ? ald(p1 + 64) : ~0ull;
      int spin = 0;
      while (((unsigned)(v1 >> 32) < tagB) | ((unsigned)(v2 >> 32) < tagB)) {
        if (++spin > 2) __builtin_amdgcn_s_sleep(1);
        v1 = ald(p1); if (two) v2 = ald(p1 + 64);
      }
      float x1 = __uint_as_float((unsigned)v1);
      float x2 = two ? __uint_as_float((unsigned)v2) : -3.0e38f;
      float m = fmaxf(x1, x2);
      #pragma unroll
      for (int o = 32; o; o >>= 1) m = fmaxf(m, __shfl_xor(m, o, 64));
      float e1 = expf(x1 - m);
      float e2 = two ? expf(x2 - m) : 0.f;
      float ss = e1 + e2;
      #pragma unroll
      for (int o = 32; o; o >>= 1) ss += __shfl_xor(ss, o, 64);
      float inv = 1.f / ss;
      float* dst = (lw == 0) ? s_ar : (lw == 1) ? s_awa : s_awm;
      dst[lane] = e1 * inv;
      if (two) dst[64 + lane] = e2 * inv;
    } else if (lw == 3) {
      float x = -3.0e38f;
      if (lane < 3) {
        const unsigned long long* p = bc + 1324 + lane;
        unsigned long long v = ald(p);
        int spin = 0;
        while ((unsigned)(v >> 32) < tagB) {
          if (++spin > 2) __builtin_amdgcn_s_sleep(1);
          v = ald(p);
        }
        x = __uint_as_float((unsigned)v);
      }
      float m = x;
      #pragma unroll
      for (int o = 32; o; o >>= 1) m = fmaxf(m, __shfl_xor(m, o, 64));
      float e = (lane < 3) ? expf(x - m) : 0.f;
      float ss = e;
      #pragma unroll
      for (int o = 32; o; o >>= 1) ss += __shfl_xor(ss, o, 64);
      if (lane < 3) s_aw[lane] = e / ss;
    } else {
      int base = tid - 256;              // 0..255, 4 slots each
      const unsigned long long* p = bc + base;
      unsigned long long v0 = ald(p), v1 = ald(p + 256), v2 = ald(p + 512), v3 = ald(p + 768);
      int spin = 0;
      while (((unsigned)(v0 >> 32) < tagB) | ((unsigned)(v1 >> 32) < tagB) |
             ((unsigned)(v2 >> 32) < tagB) | ((unsigned)(v3 >> 32) < tagB)) {
        if (++spin > 2) __builtin_amdgcn_s_sleep(1);
        v0 = ald(p); v1 = ald(p + 256); v2 = ald(p + 512); v3 = ald(p + 768);
      }
      s_c[base]       = __uint_as_float((unsigned)v0);
      s_c[base + 256] = __uint_as_float((unsigned)v1);
      s_c[base + 512] = __uint_as_float((unsigned)v2);
      s_c[base + 768] = __uint_as_float((unsigned)v3);
    }
    __syncthreads();   // SYNC1

    // ---- owned phase: ONE parallel round, publish h' BEFORE G update ----
    unsigned long long* cout = a.carryT + (size_t)((t + 1) & 1) * 1536;
    if (g < OWNB) {
      const float aw0 = s_aw[0], aw1 = s_aw[1], aw2 = s_aw[2];
      float uA, uM;
      dot16_2x512(s_TWu + (size_t)g * WPAD, s_c, s_c + 512, gl, uA, uM);

      float* grow = s_G + g * 112;
      float gv[7];
      float contrib = 0.f;
      #pragma unroll
      for (int k = 0; k < 7; ++k) {
        int idx = gl + 16 * k;           // pads 100..111 hold zeros
        gv[k] = grow[idx];
        contrib += s_ar[idx] * gv[k];
      }
      contrib = rsum16(contrib);
      if (!gl) {
        float h = fmaxf(contrib + whv + preO + biasO, 0.f);
        if (ownHsel == 0) {
          a.out[(size_t)t * 512 + ownJ] = h;
          gstTag(cout + 1024 + ownJ, h, tagB + 1);
        } else if (ownHsel == 1) {
          gstTag(cout + ownJ, h, tagB + 1);
        } else {
          gstTag(cout + 512 + ownJ, h, tagB + 1);
        }
      }
      #pragma unroll
      for (int k = 0; k < 7; ++k) {
        int idx = gl + 16 * k;
        grow[idx] = aw0 * gv[k] + aw1 * s_awa[idx] * uA + aw2 * s_awm[idx] * uM;
      }
    }
    // NO SYNC2: a wave can only pass the carry poll of step t+1 after every
    // wave (globally, incl. own block) executed its h'-publish, which is
    // program-order after all step-t reads of s_x/s_c/s_ar/s_awa/s_aw;
    // SYNC0(t+1) then fences the deferred G-update against phase-B rewrites.
    // Next-step LDS rewrites all occur after SYNC0(t+1)/within phase B.
  }
}

// ---------------- host ----------------
extern "C" void kernel_launch(void* const* d_in, const int* in_sizes, int n_in,
                              void* d_out, int out_size, void* d_ws, size_t ws_size,
                              hipStream_t stream) {
  const float* Xa    = (const float*)d_in[0];
  const float* Xm    = (const float*)d_in[1];
  const float* W_ca  = (const float*)d_in[2];  const float* b_ca  = (const float*)d_in[3];
  const float* W_cm  = (const float*)d_in[4];  const float* b_cm  = (const float*)d_in[5];
  const float* W_wp  = (const float*)d_in[6];  const float* b_wp  = (const float*)d_in[7];
  const float* W_wpa = (const float*)d_in[8];  const float* b_wpa = (const float*)d_in[9];
  const float* W_wpm = (const float*)d_in[10]; const float* b_wpm = (const float*)d_in[11];
  const float* W_rp  = (const float*)d_in[12]; const float* b_rp  = (const float*)d_in[13];
  const float* W_rh  = (const float*)d_in[14]; const float* b_rh  = (const float*)d_in[15];
  const float* W_rha = (const float*)d_in[16]; const float* b_rha = (const float*)d_in[17];
  const float* W_rhm = (const float*)d_in[18]; const float* b_rhm = (const float*)d_in[19];

  int nT = out_size / HS;   // 4096
  float* ws = (float*)d_ws;

  initK<<<dim3(64), dim3(256), 0, stream>>>(
      (unsigned long long*)(ws + OFF_CARRY),
      (unsigned long long*)(ws + OFF_BCAST));

  dim3 tb(32, 8);
  auto tg = [](int R, int C) { return dim3((C + 31) / 32, (R + 31) / 32); };
  transK<<<tg(1536, 100), tb, 0, stream>>>(W_rp,                       ws + OFF_TWrp,  1536, 100);
  transK<<<tg(1536, 3),   tb, 0, stream>>>(W_wp,                       ws + OFF_TWwp,  1536, 3);
  transK<<<tg(512, 100),  tb, 0, stream>>>(W_wpa,                      ws + OFF_TWwpa, 512, 100);
  transK<<<tg(512, 100),  tb, 0, stream>>>(W_wpm,                      ws + OFF_TWwpm, 512, 100);
  transK<<<tg(512, 512),  tb, 0, stream>>>(W_ca,                       ws + OFF_TWca,  512, 512);
  transK<<<tg(512, 512),  tb, 0, stream>>>(W_cm,                       ws + OFF_TWcm,  512, 512);
  transK<<<tg(512, 512),  tb, 0, stream>>>(W_rh  + 512 * 512,          ws + OFF_TWh0,  512, 512);
  transK<<<tg(512, 512),  tb, 0, stream>>>(W_rha + (size_t)2560 * 512, ws + OFF_TWh1,  512, 512);
  transK<<<tg(512, 512),  tb, 0, stream>>>(W_rhm + (size_t)2560 * 512, ws + OFF_TWh2,  512, 512);
  transK<<<tg(512, 512),  tb, 0, stream>>>(W_rh,                       ws + OFF_TWu0,  512, 512);
  transK<<<tg(512, 512),  tb, 0, stream>>>(W_rha + (size_t)2048 * 512, ws + OFF_TWu1,  512, 512);
  transK<<<tg(512, 512),  tb, 0, stream>>>(W_rhm + (size_t)2048 * 512, ws + OFF_TWu2,  512, 512);

  int tB = nT / 128;
  gemm128<<<dim3(4, tB), dim3(256), 0, stream>>>(Xa, W_ca + (size_t)512 * 512, ws + OFF_PAca);
  gemm128<<<dim3(4, tB), dim3(256), 0, stream>>>(Xm, W_cm + (size_t)512 * 512, ws + OFF_PMcm);
  gemm128<<<dim3(4, tB), dim3(256), 0, stream>>>(Xa, W_rha,                    ws + OFF_PArha);
  gemm128<<<dim3(4, tB), dim3(256), 0, stream>>>(Xm, W_rhm,                    ws + OFF_PMrhm);
  int tB64 = nT / 64;
  gemmK<<<dim3(2, tB64), dim3(256), 0, stream>>>(Xa, W_wpa + (size_t)512 * 100, ws + OFF_PAwpa, 100);
  gemmK<<<dim3(2, tB64), dim3(256), 0, stream>>>(Xm, W_wpm + (size_t)512 * 100, ws + OFF_PMwpm, 100);

  RArgs a;
  a.TWrp  = ws + OFF_TWrp;  a.TWwp  = ws + OFF_TWwp;
  a.TWwpa = ws + OFF_TWwpa; a.TWwpm = ws + OFF_TWwpm;
  a.TWca  = ws + OFF_TWca;  a.TWcm  = ws + OFF_TWcm;
  a.TWh0  = ws + OFF_TWh0;  a.TWh1  = ws + OFF_TWh1;  a.TWh2 = ws + OFF_TWh2;
  a.TWu0  = ws + OFF_TWu0;  a.TWu1  = ws + OFF_TWu1;  a.TWu2 = ws + OFF_TWu2;
  a.PAca  = ws + OFF_PAca;  a.PMcm  = ws + OFF_PMcm;
  a.PArha = ws + OFF_PArha; a.PMrhm = ws + OFF_PMrhm;
  a.PAwpa = ws + OFF_PAwpa; a.PMwpm = ws + OFF_PMwpm;
  a.b_ca = b_ca; a.b_cm = b_cm; a.b_wp = b_wp; a.b_wpa = b_wpa; a.b_wpm = b_wpm;
  a.b_rp = b_rp; a.b_rh = b_rh; a.b_rha = b_rha; a.b_rhm = b_rhm;
  a.carryT = (unsigned long long*)(ws + OFF_CARRY);
  a.bcast  = (unsigned long long*)(ws + OFF_BCAST);
  a.out    = (float*)d_out;
  a.nT     = nT;

  recurK<<<dim3(GBLK), dim3(TPB), 0, stream>>>(a);
}

// Round 5
// 24597.580 us; speedup vs baseline: 5.1323x; 1.0965x over previous
//
#include <hip/hip_runtime.h>
#include <cstdint>
#include <cstddef>

#define HS 512

constexpr int TPB  = 512;            // 8 waves/block
constexpr int GBLK = 64;
constexpr int OWNB = 24;             // owned carry rows per block (one per 16-lane group)
constexpr int WPAD = 516;            // padded LDS row stride (floats)

// ---------------- workspace layout (float offsets) ----------------
constexpr size_t OFF_TWrp  = 0;                       // [100][1536]
constexpr size_t OFF_TWwp  = OFF_TWrp  + 100*1536;    // [3][1536]
constexpr size_t OFF_TWwpa = OFF_TWwp  + 3*1536;      // [100][512]
constexpr size_t OFF_TWwpm = OFF_TWwpa + 100*512;
constexpr size_t OFF_TWca  = OFF_TWwpm + 100*512;     // [512][512]
constexpr size_t OFF_TWcm  = OFF_TWca  + 512*512;
constexpr size_t OFF_TWh0  = OFF_TWcm  + 512*512;     // W_rh[512:1024)^T   (h)
constexpr size_t OFF_TWh1  = OFF_TWh0  + 512*512;     // W_rha[2560:3072)^T (ha)
constexpr size_t OFF_TWh2  = OFF_TWh1  + 512*512;     // W_rhm[2560:3072)^T (hm)
constexpr size_t OFF_TWu0  = OFF_TWh2  + 512*512;     // W_rh[0:512)^T      (r)
constexpr size_t OFF_TWu1  = OFF_TWu0  + 512*512;     // W_rha[2048:2560)^T
constexpr size_t OFF_TWu2  = OFF_TWu1  + 512*512;     // W_rhm[2048:2560)^T
constexpr size_t OFF_PAca  = OFF_TWu2  + 512*512;     // [4096][512]
constexpr size_t OFF_PMcm  = OFF_PAca  + 4096*512;
constexpr size_t OFF_PArha = OFF_PMcm  + 4096*512;
constexpr size_t OFF_PMrhm = OFF_PArha + 4096*512;
constexpr size_t OFF_PAwpa = OFF_PMrhm + 4096*512;    // [4096][100]
constexpr size_t OFF_PMwpm = OFF_PAwpa + 4096*100;
constexpr size_t OFF_CARRY = OFF_PMwpm + 4096*100;    // u64[2][1536] tagged
constexpr size_t OFF_BCAST = OFF_CARRY + 2*1536*2;    // u64[2][1344] tagged
// bcast: [0:512) ca  [512:1024) cm  [1024:1124) grp  [1124:1224) gwpa
//        [1224:1324) gwpm  [1324:1327) wp

// ---------------- device helpers ----------------
__device__ __forceinline__ unsigned long long ald(const unsigned long long* p) {
  return __hip_atomic_load(const_cast<unsigned long long*>(p),
                           __ATOMIC_RELAXED, __HIP_MEMORY_SCOPE_AGENT);
}
__device__ __forceinline__ void gstTag(unsigned long long* p, float v, unsigned tag) {
  unsigned long long u = ((unsigned long long)tag << 32) | (unsigned long long)__float_as_uint(v);
  __hip_atomic_store(p, u, __ATOMIC_RELAXED, __HIP_MEMORY_SCOPE_AGENT);
}
__device__ __forceinline__ float xrsum(float v) {
  #pragma unroll
  for (int o = 32; o; o >>= 1) v += __shfl_xor(v, o, 64);
  return v;
}
__device__ __forceinline__ float rsum16(float v) {
  // xor masks < 16 keep exchange within the 16-lane group
  #pragma unroll
  for (int o = 8; o; o >>= 1) v += __shfl_xor(v, o, 64);
  return v;
}

template<int K4>
__device__ __forceinline__ float dotK(const float* __restrict__ w, const float* x) {
  int l = threadIdx.x & 63;
  const float4* w4 = (const float4*)w;
  const float4* x4 = (const float4*)x;
  float acc = 0.f;
  #pragma unroll
  for (int it = 0; it < K4; ++it) {
    float4 a = w4[l + 64*it];
    float4 b = x4[l + 64*it];
    acc += a.x*b.x + a.y*b.y + a.z*b.z + a.w*b.w;
  }
  return acc;
}

// 16-lane 512-dot: lane gl covers float4 slots gl, gl+16, ..., gl+112
__device__ __forceinline__ float dot16_512(const float* __restrict__ w,
                                           const float* x, int gl) {
  const float4* w4 = (const float4*)w;
  const float4* x4 = (const float4*)x;
  float acc = 0.f;
  #pragma unroll
  for (int it = 0; it < 8; ++it) {
    float4 a = w4[gl + 16*it];
    float4 b = x4[gl + 16*it];
    acc += a.x*b.x + a.y*b.y + a.z*b.z + a.w*b.w;
  }
  return acc;
}

// 16-lane dual 512-dot sharing the weight row (uA = w.c_a, uM = w.c_m)
__device__ __forceinline__ void dot16_2x512(const float* __restrict__ w,
                                            const float* xa, const float* xm,
                                            int gl, float& ra, float& rm) {
  const float4* w4 = (const float4*)w;
  const float4* a4 = (const float4*)xa;
  const float4* m4 = (const float4*)xm;
  float sa = 0.f, sm = 0.f;
  #pragma unroll
  for (int it = 0; it < 8; ++it) {
    float4 wv = w4[gl + 16*it], av = a4[gl + 16*it], mv = m4[gl + 16*it];
    sa += wv.x*av.x + wv.y*av.y + wv.z*av.z + wv.w*av.w;
    sm += wv.x*mv.x + wv.y*mv.y + wv.z*mv.z + wv.w*mv.w;
  }
  #pragma unroll
  for (int o = 8; o; o >>= 1) { sa += __shfl_xor(sa, o, 64); sm += __shfl_xor(sm, o, 64); }
  ra = sa; rm = sm;
}

// ---------------- prep kernels ----------------
__global__ void initK(unsigned long long* carryT, unsigned long long* bcast) {
  int i = blockIdx.x * blockDim.x + threadIdx.x, st = gridDim.x * blockDim.x;
  for (int k = i; k < 1536; k += st) carryT[k] = (1ull << 32);   // carry(0)=0, tag 1
  for (int k = i; k < 1536; k += st) carryT[1536 + k] = 0ull;
  for (int k = i; k < 2 * 1344; k += st) bcast[k] = 0ull;
}

__global__ void transK(const float* __restrict__ src, float* __restrict__ dst, int R, int C) {
  __shared__ float tile[32][33];
  int c0 = blockIdx.x * 32, r0 = blockIdx.y * 32;
  for (int i = threadIdx.y; i < 32; i += 8) {
    int r = r0 + i, c = c0 + threadIdx.x;
    tile[i][threadIdx.x] = (r < R && c < C) ? src[(size_t)r * C + c] : 0.f;
  }
  __syncthreads();
  for (int i = threadIdx.y; i < 32; i += 8) {
    int c = c0 + i, r = r0 + threadIdx.x;
    if (c < C && r < R) dst[(size_t)c * R + r] = tile[threadIdx.x][i];
  }
}

__global__ __launch_bounds__(256) void gemmK(const float* __restrict__ X,
                                             const float* __restrict__ W,
                                             float* __restrict__ C, int N) {
  __shared__ float As[16][68];
  __shared__ float Bs[16][68];
  int t0 = blockIdx.y * 64, n0 = blockIdx.x * 64;
  int tid = threadIdx.x, tx = tid & 15, ty = tid >> 4;
  float acc[4][4] = {};
  for (int k0 = 0; k0 < 2048; k0 += 16) {
    {
      int r = tid >> 2, c = (tid & 3) * 4;
      float4 v = *(const float4*)(X + (size_t)(t0 + r) * 2048 + k0 + c);
      As[c + 0][r] = v.x; As[c + 1][r] = v.y; As[c + 2][r] = v.z; As[c + 3][r] = v.w;
    }
    {
      int kr = tid >> 4, c = (tid & 15) * 4;
      int gcol = n0 + c;
      const float* src = W + (size_t)(k0 + kr) * N + gcol;
      #pragma unroll
      for (int i = 0; i < 4; ++i) Bs[kr][c + i] = (gcol + i < N) ? src[i] : 0.f;
    }
    __syncthreads();
    #pragma unroll
    for (int kk = 0; kk < 16; ++kk) {
      float4 a4 = *(const float4*)&As[kk][ty * 4];
      float4 b4 = *(const float4*)&Bs[kk][tx * 4];
      float av[4] = {a4.x, a4.y, a4.z, a4.w};
      float bv[4] = {b4.x, b4.y, b4.z, b4.w};
      #pragma unroll
      for (int i = 0; i < 4; ++i)
        #pragma unroll
        for (int j = 0; j < 4; ++j) acc[i][j] += av[i] * bv[j];
    }
    __syncthreads();
  }
  #pragma unroll
  for (int i = 0; i < 4; ++i)
    #pragma unroll
    for (int j = 0; j < 4; ++j) {
      int col = n0 + tx * 4 + j;
      if (col < N) C[(size_t)(t0 + ty * 4 + i) * N + col] = acc[i][j];
    }
}

__global__ __launch_bounds__(256) void gemm128(const float* __restrict__ X,
                                               const float* __restrict__ W,
                                               float* __restrict__ C) {
  __shared__ float As[8][132];
  __shared__ float Bs[8][132];
  const int N = 512;
  int t0 = blockIdx.y * 128, n0 = blockIdx.x * 128;
  int tid = threadIdx.x, tx = tid & 15, ty = tid >> 4;
  float acc[8][8] = {};
  for (int k0 = 0; k0 < 2048; k0 += 8) {
    int r = tid >> 1, c4 = (tid & 1) * 4;
    float4 va = *(const float4*)(X + (size_t)(t0 + r) * 2048 + k0 + c4);
    int kr = tid >> 5, cb = (tid & 31) * 4;
    float4 vb = *(const float4*)(W + (size_t)(k0 + kr) * N + n0 + cb);
    __syncthreads();
    As[c4 + 0][r] = va.x; As[c4 + 1][r] = va.y; As[c4 + 2][r] = va.z; As[c4 + 3][r] = va.w;
    Bs[kr][cb] = vb.x; Bs[kr][cb + 1] = vb.y; Bs[kr][cb + 2] = vb.z; Bs[kr][cb + 3] = vb.w;
    __syncthreads();
    #pragma unroll
    for (int kk = 0; kk < 8; ++kk) {
      float av[8], bv[8];
      *(float4*)av       = *(const float4*)&As[kk][ty * 8];
      *(float4*)(av + 4) = *(const float4*)&As[kk][ty * 8 + 4];
      *(float4*)bv       = *(const float4*)&Bs[kk][tx * 8];
      *(float4*)(bv + 4) = *(const float4*)&Bs[kk][tx * 8 + 4];
      #pragma unroll
      for (int i = 0; i < 8; ++i)
        #pragma unroll
        for (int j = 0; j < 8; ++j) acc[i][j] += av[i] * bv[j];
    }
  }
  #pragma unroll
  for (int i = 0; i < 8; ++i) {
    float* dst = C + (size_t)(t0 + ty * 8 + i) * N + n0 + tx * 8;
    *(float4*)dst       = *(float4*)&acc[i][0];
    *(float4*)(dst + 4) = *(float4*)&acc[i][4];
  }
}

// ---------------- persistent recurrence kernel ----------------
struct RArgs {
  const float *TWrp, *TWwp, *TWwpa, *TWwpm, *TWca, *TWcm;
  const float *TWh0, *TWh1, *TWh2, *TWu0, *TWu1, *TWu2;
  const float *PAca, *PMcm, *PArha, *PMrhm, *PAwpa, *PMwpm;
  const float *b_ca, *b_cm, *b_wp, *b_wpa, *b_wpm, *b_rp, *b_rh, *b_rha, *b_rhm;
  unsigned long long *carryT, *bcast;
  float *out;
  int nT;
};

__global__ __launch_bounds__(TPB, 1) void recurK(RArgs a) {
  const int tid  = threadIdx.x;
  const int lane = tid & 63;
  const int lw   = tid >> 6;                 // wave 0..7
  const int g    = tid >> 4;                 // 16-lane group 0..31
  const int gl   = tid & 15;
  const int b    = blockIdx.x;

  // ---- LDS (~123 KB static; gfx950 allows 160 KB/WG) ----
  __shared__ __align__(16) float s_wca[8 * WPAD];    // ca rows (cols b*8..b*8+7)
  __shared__ __align__(16) float s_wcm[8 * WPAD];
  __shared__ __align__(16) float s_wbig[2 * 1536];   // grp / wp rows
  __shared__ __align__(16) float s_wsm[4 * WPAD];    // gwpa / gwpm rows
  __shared__ __align__(16) float s_TWu[OWNB * WPAD]; // owned u-rows
  __shared__ __align__(16) float s_G[OWNB * 112];    // block-private G (padded 112)
  __shared__ __align__(16) float s_x[1536];          // carry [ha|hm|h]
  __shared__ __align__(16) float s_c[1024];          // [ca|cm]
  __shared__ float s_ar[112], s_awa[112], s_awm[112], s_aw[4];

  // ---- static assignment maps ----
  const int r0a = (b + 51) & 63;                 // gwpa rows r0a, r0a+64(if<36)
  const int r1m = (b + 25) & 63;                 // gwpm rows
  const bool big1_grp = (b < 36);
  const bool big1_wp  = (b >= 40 && b <= 42);

  // ---- stage weights into LDS (once; pads never read as data) ----
  for (int i = tid; i < 8 * WPAD; i += TPB) {
    int row = i / WPAD, col = i - row * WPAD;
    if (col < 512) {
      s_wca[i] = a.TWca[(size_t)(b * 8 + row) * 512 + col];
      s_wcm[i] = a.TWcm[(size_t)(b * 8 + row) * 512 + col];
    }
  }
  for (int i = tid; i < 1536; i += TPB) {
    s_wbig[i] = a.TWrp[(size_t)b * 1536 + i];
    float v2 = 0.f;
    if (big1_grp)      v2 = a.TWrp[(size_t)(b + 64) * 1536 + i];
    else if (big1_wp)  v2 = a.TWwp[(size_t)(b - 40) * 1536 + i];
    s_wbig[1536 + i] = v2;
  }
  for (int i = tid; i < 4 * WPAD; i += TPB) {
    int sl = i / WPAD, col = i - sl * WPAD;
    float v = 0.f;
    if (col < 512) {
      if (sl == 0)      v = a.TWwpa[(size_t)r0a * 512 + col];
      else if (sl == 1) v = (r0a < 36) ? a.TWwpa[(size_t)(r0a + 64) * 512 + col] : 0.f;
      else if (sl == 2) v = a.TWwpm[(size_t)r1m * 512 + col];
      else              v = (r1m < 36) ? a.TWwpm[(size_t)(r1m + 64) * 512 + col] : 0.f;
    }
    s_wsm[i] = v;
  }
  for (int i = tid; i < OWNB * WPAD; i += TPB) {
    int rr = i / WPAD, col = i - rr * WPAD;
    if (col < 512) {
      int q = b * OWNB + rr, hsel = q >> 9, j = q & 511;
      const float* src = (hsel == 0) ? a.TWu0 : (hsel == 1) ? a.TWu1 : a.TWu2;
      s_TWu[i] = src[(size_t)j * 512 + col];
    }
  }
  for (int i = tid; i < OWNB * 112; i += TPB) s_G[i] = 0.f;
  if (tid < 112) { s_ar[tid] = 0.f; s_awa[tid] = 0.f; s_awm[tid] = 0.f; }

  // ---- per-thread roles ----
  // phase A group jobs: waves 0-1 = ca cols, 2-3 = cm cols, 4 = small gates,
  // 5 = none (starts wh early), 6 = big0 (grp b), 7 = big1 (grp b+64 / wp)
  int dstA = -1, xoffA = 0, strideA = 512, rowA = 0;
  float biasA = 0.f;
  const float* preAPtr = nullptr;
  if (lw < 2) {
    int col = b * 8 + g; rowA = g;
    dstA = col; biasA = a.b_ca[col]; preAPtr = a.PAca + col;
  } else if (lw < 4) {
    int col = b * 8 + (g - 8); rowA = g - 8;
    dstA = 512 + col; biasA = a.b_cm[col]; preAPtr = a.PMcm + col;
  } else if (lw == 4) {
    int sl = g - 16;
    if (sl == 0)                  { rowA = 0; dstA = 1124 + r0a;      biasA = a.b_wpa[r0a];      preAPtr = a.PAwpa + r0a;      xoffA = 0;   strideA = 100; }
    else if (sl == 1 && r0a < 36) { rowA = 1; dstA = 1124 + r0a + 64; biasA = a.b_wpa[r0a + 64]; preAPtr = a.PAwpa + r0a + 64; xoffA = 0;   strideA = 100; }
    else if (sl == 2)             { rowA = 2; dstA = 1224 + r1m;      biasA = a.b_wpm[r1m];      preAPtr = a.PMwpm + r1m;      xoffA = 512; strideA = 100; }
    else if (sl == 3 && r1m < 36) { rowA = 3; dstA = 1224 + r1m + 64; biasA = a.b_wpm[r1m + 64]; preAPtr = a.PMwpm + r1m + 64; xoffA = 512; strideA = 100; }
  }
  int dstBig = -1, bigOff = 0;
  float biasBig = 0.f;
  if (lw == 6) { dstBig = 1024 + b; biasBig = a.b_rp[b]; bigOff = 0; }
  else if (lw == 7) {
    if (big1_grp)      { dstBig = 1024 + b + 64;  biasBig = a.b_rp[b + 64]; bigOff = 1536; }
    else if (big1_wp)  { dstBig = 1324 + (b - 40); biasBig = a.b_wp[b - 40]; bigOff = 1536; }
  }
  // owned / wh: group g < 24 owns carry row q = b*24+g (wh row == owned row)
  int ownHsel = 0, ownJ = 0, whXo = 0;
  float biasO = 0.f;
  const float* preOPtr = nullptr;
  const float* whPtr = nullptr;
  if (g < OWNB) {
    int q = b * OWNB + g, hsel = q >> 9, j = q & 511;
    ownHsel = hsel; ownJ = j;
    if (hsel == 0)      { biasO = a.b_rh[j];                           whPtr = a.TWh0 + (size_t)j * 512; whXo = 1024; }
    else if (hsel == 1) { biasO = a.b_rha[j]; preOPtr = a.PArha + j;   whPtr = a.TWh1 + (size_t)j * 512; whXo = 0; }
    else                { biasO = a.b_rhm[j]; preOPtr = a.PMrhm + j;   whPtr = a.TWh2 + (size_t)j * 512; whXo = 512; }
  }
  __syncthreads();

  // ---- prologue: software-pipelined per-step scalars (value for t=0) ----
  float preA_c = preAPtr ? preAPtr[0] : 0.f;
  float preO_c = preOPtr ? preOPtr[0] : 0.f;

  // ---------------- time loop ----------------
  float whv = 0.f;
  for (int t = 0; t < a.nT; ++t) {
    const unsigned tagB = (unsigned)t + 1;
    unsigned long long* bc = a.bcast + (size_t)(t & 1) * 1344;

    // ---- poll carry(t): 3 slots/thread ----
    {
      const unsigned long long* cin = a.carryT + (size_t)(t & 1) * 1536;
      int i0 = tid, i1 = tid + 512, i2 = tid + 1024;
      unsigned long long v0 = ald(cin + i0), v1 = ald(cin + i1), v2 = ald(cin + i2);
      while (((unsigned)(v0 >> 32) < tagB) | ((unsigned)(v1 >> 32) < tagB) |
             ((unsigned)(v2 >> 32) < tagB)) {
        __builtin_amdgcn_s_sleep(1);
        v0 = ald(cin + i0); v1 = ald(cin + i1); v2 = ald(cin + i2);
      }
      s_x[i0] = __uint_as_float((unsigned)v0);
      s_x[i1] = __uint_as_float((unsigned)v1);
      s_x[i2] = __uint_as_float((unsigned)v2);
    }
    __syncthreads();   // SYNC0

    // issue NEXT step's prefetches now: they get the whole step (~5 us) to
    // land, so the HBM miss can never stall phase A / owned phase.
    const int tn = (t + 1 < a.nT) ? t + 1 : t;
    float preA_n = preAPtr ? preAPtr[(size_t)tn * strideA] : 0.f;
    float preO_n = preOPtr ? preOPtr[(size_t)tn * 512] : 0.f;

    // ---- phase A: all critical publishes in ONE parallel round ----
    if (lw < 2) {
      float v = rsum16(dot16_512(s_wca + rowA * WPAD, s_x, gl));
      if (!gl) gstTag(bc + dstA, fmaxf(v + preA_c + biasA, 0.f), tagB);
    } else if (lw < 4) {
      float v = rsum16(dot16_512(s_wcm + rowA * WPAD, s_x + 512, gl));
      if (!gl) gstTag(bc + dstA, fmaxf(v + preA_c + biasA, 0.f), tagB);
    } else if (lw == 4) {
      if (dstA >= 0) {
        float v = rsum16(dot16_512(s_wsm + rowA * WPAD, s_x + xoffA, gl));
        if (!gl) gstTag(bc + dstA, v + preA_c + biasA, tagB);
      }
    } else if (lw >= 6) {
      if (dstBig >= 0) {
        float v = xrsum(dotK<6>(s_wbig + bigOff, s_x));
        if (!lane) gstTag(bc + dstBig, v + biasBig, tagB);
      }
    }
    // wh dots from L2 (off the inter-block critical path); result stays in reg
    if (g < OWNB) whv = rsum16(dot16_512(whPtr, s_x + whXo, gl));

    // ---- phase B polls: waves 0-3 softmax groups, waves 4-7 gather c ----
    if (lw < 3) {
      int base = 1024 + lw * 100;       // grp / gwpa / gwpm
      const unsigned long long* p1 = bc + base + lane;
      bool two = lane < 36;
      unsigned long long v1 = ald(p1);
      unsigned long long v2 = two ? ald(p1 + 64) : ~0ull;
      while (((unsigned)(v1 >> 32) < tagB) | ((unsigned)(v2 >> 32) < tagB)) {
        __builtin_amdgcn_s_sleep(1);
        v1 = ald(p1); if (two) v2 = ald(p1 + 64);
      }
      float x1 = __uint_as_float((unsigned)v1);
      float x2 = two ? __uint_as_float((unsigned)v2) : -3.0e38f;
      float m = fmaxf(x1, x2);
      #pragma unroll
      for (int o = 32; o; o >>= 1) m = fmaxf(m, __shfl_xor(m, o, 64));
      float e1 = expf(x1 - m);
      float e2 = two ? expf(x2 - m) : 0.f;
      float ss = e1 + e2;
      #pragma unroll
      for (int o = 32; o; o >>= 1) ss += __shfl_xor(ss, o, 64);
      float inv = 1.f / ss;
      float* dst = (lw == 0) ? s_ar : (lw == 1) ? s_awa : s_awm;
      dst[lane] = e1 * inv;
      if (two) dst[64 + lane] = e2 * inv;
    } else if (lw == 3) {
      float x = -3.0e38f;
      if (lane < 3) {
        const unsigned long long* p = bc + 1324 + lane;
        unsigned long long v = ald(p);
        while ((unsigned)(v >> 32) < tagB) { __builtin_amdgcn_s_sleep(1); v = ald(p); }
        x = __uint_as_float((unsigned)v);
      }
      float m = x;
      #pragma unroll
      for (int o = 32; o; o >>= 1) m = fmaxf(m, __shfl_xor(m, o, 64));
      float e = (lane < 3) ? expf(x - m) : 0.f;
      float ss = e;
      #pragma unroll
      for (int o = 32; o; o >>= 1) ss += __shfl_xor(ss, o, 64);
      if (lane < 3) s_aw[lane] = e / ss;
    } else {
      int base = tid - 256;              // 0..255, 4 slots each
      const unsigned long long* p = bc + base;
      unsigned long long v0 = ald(p), v1 = ald(p + 256), v2 = ald(p + 512), v3 = ald(p + 768);
      while (((unsigned)(v0 >> 32) < tagB) | ((unsigned)(v1 >> 32) < tagB) |
             ((unsigned)(v2 >> 32) < tagB) | ((unsigned)(v3 >> 32) < tagB)) {
        __builtin_amdgcn_s_sleep(1);
        v0 = ald(p); v1 = ald(p + 256); v2 = ald(p + 512); v3 = ald(p + 768);
      }
      s_c[base]       = __uint_as_float((unsigned)v0);
      s_c[base + 256] = __uint_as_float((unsigned)v1);
      s_c[base + 512] = __uint_as_float((unsigned)v2);
      s_c[base + 768] = __uint_as_float((unsigned)v3);
    }
    __syncthreads();   // SYNC1

    // ---- owned phase: ONE parallel round, publish h' BEFORE G update ----
    unsigned long long* cout = a.carryT + (size_t)((t + 1) & 1) * 1536;
    if (g < OWNB) {
      const float aw0 = s_aw[0], aw1 = s_aw[1], aw2 = s_aw[2];
      float uA, uM;
      dot16_2x512(s_TWu + (size_t)g * WPAD, s_c, s_c + 512, gl, uA, uM);

      float* grow = s_G + g * 112;
      float gv[7];
      float contrib = 0.f;
      #pragma unroll
      for (int k = 0; k < 7; ++k) {
        int idx = gl + 16 * k;           // pads 100..111 hold zeros
        gv[k] = grow[idx];
        contrib += s_ar[idx] * gv[k];
      }
      contrib = rsum16(contrib);
      if (!gl) {
        float h = fmaxf(contrib + whv + preO_c + biasO, 0.f);
        if (ownHsel == 0) {
          a.out[(size_t)t * 512 + ownJ] = h;
          gstTag(cout + 1024 + ownJ, h, tagB + 1);
        } else if (ownHsel == 1) {
          gstTag(cout + ownJ, h, tagB + 1);
        } else {
          gstTag(cout + 512 + ownJ, h, tagB + 1);
        }
      }
      #pragma unroll
      for (int k = 0; k < 7; ++k) {
        int idx = gl + 16 * k;
        grow[idx] = aw0 * gv[k] + aw1 * s_awa[idx] * uA + aw2 * s_awm[idx] * uM;
      }
    }
    // NO SYNC2: a wave can only pass the carry poll of step t+1 after every
    // wave (globally, incl. own block) executed its h'-publish, which is
    // program-order after all step-t reads of s_x/s_c/s_ar/s_awa/s_aw;
    // SYNC0(t+1) then fences the deferred G-update against phase-B rewrites.

    // rotate the pipelined prefetch registers
    preA_c = preA_n;
    preO_c = preO_n;
  }
}

// ---------------- host ----------------
extern "C" void kernel_launch(void* const* d_in, const int* in_sizes, int n_in,
                              void* d_out, int out_size, void* d_ws, size_t ws_size,
                              hipStream_t stream) {
  const float* Xa    = (const float*)d_in[0];
  const float* Xm    = (const float*)d_in[1];
  const float* W_ca  = (const float*)d_in[2];  const float* b_ca  = (const float*)d_in[3];
  const float* W_cm  = (const float*)d_in[4];  const float* b_cm  = (const float*)d_in[5];
  const float* W_wp  = (const float*)d_in[6];  const float* b_wp  = (const float*)d_in[7];
  const float* W_wpa = (const float*)d_in[8];  const float* b_wpa = (const float*)d_in[9];
  const float* W_wpm = (const float*)d_in[10]; const float* b_wpm = (const float*)d_in[11];
  const float* W_rp  = (const float*)d_in[12]; const float* b_rp  = (const float*)d_in[13];
  const float* W_rh  = (const float*)d_in[14]; const float* b_rh  = (const float*)d_in[15];
  const float* W_rha = (const float*)d_in[16]; const float* b_rha = (const float*)d_in[17];
  const float* W_rhm = (const float*)d_in[18]; const float* b_rhm = (const float*)d_in[19];

  int nT = out_size / HS;   // 4096
  float* ws = (float*)d_ws;

  initK<<<dim3(64), dim3(256), 0, stream>>>(
      (unsigned long long*)(ws + OFF_CARRY),
      (unsigned long long*)(ws + OFF_BCAST));

  dim3 tb(32, 8);
  auto tg = [](int R, int C) { return dim3((C + 31) / 32, (R + 31) / 32); };
  transK<<<tg(1536, 100), tb, 0, stream>>>(W_rp,                       ws + OFF_TWrp,  1536, 100);
  transK<<<tg(1536, 3),   tb, 0, stream>>>(W_wp,                       ws + OFF_TWwp,  1536, 3);
  transK<<<tg(512, 100),  tb, 0, stream>>>(W_wpa,                      ws + OFF_TWwpa, 512, 100);
  transK<<<tg(512, 100),  tb, 0, stream>>>(W_wpm,                      ws + OFF_TWwpm, 512, 100);
  transK<<<tg(512, 512),  tb, 0, stream>>>(W_ca,                       ws + OFF_TWca,  512, 512);
  transK<<<tg(512, 512),  tb, 0, stream>>>(W_cm,                       ws + OFF_TWcm,  512, 512);
  transK<<<tg(512, 512),  tb, 0, stream>>>(W_rh  + 512 * 512,          ws + OFF_TWh0,  512, 512);
  transK<<<tg(512, 512),  tb, 0, stream>>>(W_rha + (size_t)2560 * 512, ws + OFF_TWh1,  512, 512);
  transK<<<tg(512, 512),  tb, 0, stream>>>(W_rhm + (size_t)2560 * 512, ws + OFF_TWh2,  512, 512);
  transK<<<tg(512, 512),  tb, 0, stream>>>(W_rh,                       ws + OFF_TWu0,  512, 512);
  transK<<<tg(512, 512),  tb, 0, stream>>>(W_rha + (size_t)2048 * 512, ws + OFF_TWu1,  512, 512);
  transK<<<tg(512, 512),  tb, 0, stream>>>(W_rhm + (size_t)2048 * 512, ws + OFF_TWu2,  512, 512);

  int tB = nT / 128;
  gemm128<<<dim3(4, tB), dim3(256), 0, stream>>>(Xa, W_ca + (size_t)512 * 512, ws + OFF_PAca);
  gemm128<<<dim3(4, tB), dim3(256), 0, stream>>>(Xm, W_cm + (size_t)512 * 512, ws + OFF_PMcm);
  gemm128<<<dim3(4, tB), dim3(256), 0, stream>>>(Xa, W_rha,                    ws + OFF_PArha);
  gemm128<<<dim3(4, tB), dim3(256), 0, stream>>>(Xm, W_rhm,                    ws + OFF_PMrhm);
  int tB64 = nT / 64;
  gemmK<<<dim3(2, tB64), dim3(256), 0, stream>>>(Xa, W_wpa + (size_t)512 * 100, ws + OFF_PAwpa, 100);
  gemmK<<<dim3(2, tB64), dim3(256), 0, stream>>>(Xm, W_wpm + (size_t)512 * 100, ws + OFF_PMwpm, 100);

  RArgs a;
  a.TWrp  = ws + OFF_TWrp;  a.TWwp  = ws + OFF_TWwp;
  a.TWwpa = ws + OFF_TWwpa; a.TWwpm = ws + OFF_TWwpm;
  a.TWca  = ws + OFF_TWca;  a.TWcm  = ws + OFF_TWcm;
  a.TWh0  = ws + OFF_TWh0;  a.TWh1  = ws + OFF_TWh1;  a.TWh2 = ws + OFF_TWh2;
  a.TWu0  = ws + OFF_TWu0;  a.TWu1  = ws + OFF_TWu1;  a.TWu2 = ws + OFF_TWu2;
  a.PAca  = ws + OFF_PAca;  a.PMcm  = ws + OFF_PMcm;
  a.PArha = ws + OFF_PArha; a.PMrhm = ws + OFF_PMrhm;
  a.PAwpa = ws + OFF_PAwpa; a.PMwpm = ws + OFF_PMwpm;
  a.b_ca = b_ca; a.b_cm = b_cm; a.b_wp = b_wp; a.b_wpa = b_wpa; a.b_wpm = b_wpm;
  a.b_rp = b_rp; a.b_rh = b_rh; a.b_rha = b_rha; a.b_rhm = b_rhm;
  a.carryT = (unsigned long long*)(ws + OFF_CARRY);
  a.bcast  = (unsigned long long*)(ws + OFF_BCAST);
  a.out    = (float*)d_out;
  a.nT     = nT;

  recurK<<<dim3(GBLK), dim3(TPB), 0, stream>>>(a);
}

// Round 6
// 22880.969 us; speedup vs baseline: 5.5173x; 1.0750x over previous
//
#include <hip/hip_runtime.h>
#include <cstdint>
#include <cstddef>

#define HS 512

constexpr int TPB  = 512;            // 8 waves/block
constexpr int GBLK = 64;
constexpr int OWNB = 24;             // owned carry rows per block (one per 16-lane group)

// ---------------- workspace layout (float offsets) ----------------
constexpr size_t OFF_TWrp  = 0;                       // [100][1536]
constexpr size_t OFF_TWwp  = OFF_TWrp  + 100*1536;    // [3][1536]
constexpr size_t OFF_TWwpa = OFF_TWwp  + 3*1536;      // [100][512]
constexpr size_t OFF_TWwpm = OFF_TWwpa + 100*512;
constexpr size_t OFF_TWca  = OFF_TWwpm + 100*512;     // [512][512]
constexpr size_t OFF_TWcm  = OFF_TWca  + 512*512;
constexpr size_t OFF_TWh0  = OFF_TWcm  + 512*512;     // W_rh[512:1024)^T   (h)
constexpr size_t OFF_TWh1  = OFF_TWh0  + 512*512;     // W_rha[2560:3072)^T (ha)
constexpr size_t OFF_TWh2  = OFF_TWh1  + 512*512;     // W_rhm[2560:3072)^T (hm)
constexpr size_t OFF_TWu0  = OFF_TWh2  + 512*512;     // W_rh[0:512)^T      (r)
constexpr size_t OFF_TWu1  = OFF_TWu0  + 512*512;     // W_rha[2048:2560)^T
constexpr size_t OFF_TWu2  = OFF_TWu1  + 512*512;     // W_rhm[2048:2560)^T
constexpr size_t OFF_PAca  = OFF_TWu2  + 512*512;     // [4096][512]
constexpr size_t OFF_PMcm  = OFF_PAca  + 4096*512;
constexpr size_t OFF_PArha = OFF_PMcm  + 4096*512;
constexpr size_t OFF_PMrhm = OFF_PArha + 4096*512;
constexpr size_t OFF_PAwpa = OFF_PMrhm + 4096*512;    // [4096][100]
constexpr size_t OFF_PMwpm = OFF_PAwpa + 4096*100;
constexpr size_t OFF_CARRY = OFF_PMwpm + 4096*100;    // u64[2][1536] tagged
constexpr size_t OFF_BCAST = OFF_CARRY + 2*1536*2;    // u64[2][1344] tagged
// bcast: [0:512) ca  [512:1024) cm  [1024:1124) grp  [1124:1224) gwpa
//        [1224:1324) gwpm  [1324:1327) wp

// ---------------- device helpers ----------------
__device__ __forceinline__ unsigned long long ald(const unsigned long long* p) {
  return __hip_atomic_load(const_cast<unsigned long long*>(p),
                           __ATOMIC_RELAXED, __HIP_MEMORY_SCOPE_AGENT);
}
__device__ __forceinline__ void gstTag(unsigned long long* p, float v, unsigned tag) {
  unsigned long long u = ((unsigned long long)tag << 32) | (unsigned long long)__float_as_uint(v);
  __hip_atomic_store(p, u, __ATOMIC_RELAXED, __HIP_MEMORY_SCOPE_AGENT);
}
__device__ __forceinline__ float xrsum(float v) {
  #pragma unroll
  for (int o = 32; o; o >>= 1) v += __shfl_xor(v, o, 64);
  return v;
}
__device__ __forceinline__ float rsum16(float v) {
  // xor masks < 16 keep exchange within the 16-lane group
  #pragma unroll
  for (int o = 8; o; o >>= 1) v += __shfl_xor(v, o, 64);
  return v;
}

// ---------------- prep kernels ----------------
__global__ void initK(unsigned long long* carryT, unsigned long long* bcast) {
  int i = blockIdx.x * blockDim.x + threadIdx.x, st = gridDim.x * blockDim.x;
  for (int k = i; k < 1536; k += st) carryT[k] = (1ull << 32);   // carry(0)=0, tag 1
  for (int k = i; k < 1536; k += st) carryT[1536 + k] = 0ull;
  for (int k = i; k < 2 * 1344; k += st) bcast[k] = 0ull;
}

__global__ void transK(const float* __restrict__ src, float* __restrict__ dst, int R, int C) {
  __shared__ float tile[32][33];
  int c0 = blockIdx.x * 32, r0 = blockIdx.y * 32;
  for (int i = threadIdx.y; i < 32; i += 8) {
    int r = r0 + i, c = c0 + threadIdx.x;
    tile[i][threadIdx.x] = (r < R && c < C) ? src[(size_t)r * C + c] : 0.f;
  }
  __syncthreads();
  for (int i = threadIdx.y; i < 32; i += 8) {
    int c = c0 + i, r = r0 + threadIdx.x;
    if (c < C && r < R) dst[(size_t)c * R + r] = tile[threadIdx.x][i];
  }
}

__global__ __launch_bounds__(256) void gemmK(const float* __restrict__ X,
                                             const float* __restrict__ W,
                                             float* __restrict__ C, int N) {
  __shared__ float As[16][68];
  __shared__ float Bs[16][68];
  int t0 = blockIdx.y * 64, n0 = blockIdx.x * 64;
  int tid = threadIdx.x, tx = tid & 15, ty = tid >> 4;
  float acc[4][4] = {};
  for (int k0 = 0; k0 < 2048; k0 += 16) {
    {
      int r = tid >> 2, c = (tid & 3) * 4;
      float4 v = *(const float4*)(X + (size_t)(t0 + r) * 2048 + k0 + c);
      As[c + 0][r] = v.x; As[c + 1][r] = v.y; As[c + 2][r] = v.z; As[c + 3][r] = v.w;
    }
    {
      int kr = tid >> 4, c = (tid & 15) * 4;
      int gcol = n0 + c;
      const float* src = W + (size_t)(k0 + kr) * N + gcol;
      #pragma unroll
      for (int i = 0; i < 4; ++i) Bs[kr][c + i] = (gcol + i < N) ? src[i] : 0.f;
    }
    __syncthreads();
    #pragma unroll
    for (int kk = 0; kk < 16; ++kk) {
      float4 a4 = *(const float4*)&As[kk][ty * 4];
      float4 b4 = *(const float4*)&Bs[kk][tx * 4];
      float av[4] = {a4.x, a4.y, a4.z, a4.w};
      float bv[4] = {b4.x, b4.y, b4.z, b4.w};
      #pragma unroll
      for (int i = 0; i < 4; ++i)
        #pragma unroll
        for (int j = 0; j < 4; ++j) acc[i][j] += av[i] * bv[j];
    }
    __syncthreads();
  }
  #pragma unroll
  for (int i = 0; i < 4; ++i)
    #pragma unroll
    for (int j = 0; j < 4; ++j) {
      int col = n0 + tx * 4 + j;
      if (col < N) C[(size_t)(t0 + ty * 4 + i) * N + col] = acc[i][j];
    }
}

__global__ __launch_bounds__(256) void gemm128(const float* __restrict__ X,
                                               const float* __restrict__ W,
                                               float* __restrict__ C) {
  __shared__ float As[8][132];
  __shared__ float Bs[8][132];
  const int N = 512;
  int t0 = blockIdx.y * 128, n0 = blockIdx.x * 128;
  int tid = threadIdx.x, tx = tid & 15, ty = tid >> 4;
  float acc[8][8] = {};
  for (int k0 = 0; k0 < 2048; k0 += 8) {
    int r = tid >> 1, c4 = (tid & 1) * 4;
    float4 va = *(const float4*)(X + (size_t)(t0 + r) * 2048 + k0 + c4);
    int kr = tid >> 5, cb = (tid & 31) * 4;
    float4 vb = *(const float4*)(W + (size_t)(k0 + kr) * N + n0 + cb);
    __syncthreads();
    As[c4 + 0][r] = va.x; As[c4 + 1][r] = va.y; As[c4 + 2][r] = va.z; As[c4 + 3][r] = va.w;
    Bs[kr][cb] = vb.x; Bs[kr][cb + 1] = vb.y; Bs[kr][cb + 2] = vb.z; Bs[kr][cb + 3] = vb.w;
    __syncthreads();
    #pragma unroll
    for (int kk = 0; kk < 8; ++kk) {
      float av[8], bv[8];
      *(float4*)av       = *(const float4*)&As[kk][ty * 8];
      *(float4*)(av + 4) = *(const float4*)&As[kk][ty * 8 + 4];
      *(float4*)bv       = *(const float4*)&Bs[kk][tx * 8];
      *(float4*)(bv + 4) = *(const float4*)&Bs[kk][tx * 8 + 4];
      #pragma unroll
      for (int i = 0; i < 8; ++i)
        #pragma unroll
        for (int j = 0; j < 8; ++j) acc[i][j] += av[i] * bv[j];
    }
  }
  #pragma unroll
  for (int i = 0; i < 8; ++i) {
    float* dst = C + (size_t)(t0 + ty * 8 + i) * N + n0 + tx * 8;
    *(float4*)dst       = *(float4*)&acc[i][0];
    *(float4*)(dst + 4) = *(float4*)&acc[i][4];
  }
}

// ---------------- persistent recurrence kernel ----------------
struct RArgs {
  const float *TWrp, *TWwp, *TWwpa, *TWwpm, *TWca, *TWcm;
  const float *TWh0, *TWh1, *TWh2, *TWu0, *TWu1, *TWu2;
  const float *PAca, *PMcm, *PArha, *PMrhm, *PAwpa, *PMwpm;
  const float *b_ca, *b_cm, *b_wp, *b_wpa, *b_wpm, *b_rp, *b_rh, *b_rha, *b_rhm;
  unsigned long long *carryT, *bcast;
  float *out;
  int nT;
};

__global__ __launch_bounds__(TPB, 1) void recurK(RArgs a) {
  const int tid  = threadIdx.x;
  const int lane = tid & 63;
  const int lw   = tid >> 6;                 // wave 0..7
  const int g    = tid >> 4;                 // 16-lane group 0..31
  const int gl   = tid & 15;
  const int b    = blockIdx.x;

  // ---- LDS (~12 KB: all weights + G live in registers now) ----
  __shared__ __align__(16) float s_x[1536];          // carry [ha|hm|h]
  __shared__ __align__(16) float s_c[1024];          // [ca|cm]
  __shared__ float s_ar[112], s_awa[112], s_awm[112], s_aw[4];

  // ---- static assignment maps ----
  const int r0a = (b + 51) & 63;                 // gwpa rows r0a, r0a+64(if<36)
  const int r1m = (b + 25) & 63;                 // gwpm rows
  const bool big1_grp = (b < 36);
  const bool big1_wp  = (b >= 40 && b <= 42);

  if (tid < 112) { s_ar[tid] = 0.f; s_awa[tid] = 0.f; s_awm[tid] = 0.f; }

  // ---- per-thread roles ----
  // phase A group jobs: waves 0-1 = ca cols, 2-3 = cm cols, 4 = small gates,
  // 5 = none (does wh only), 6 = big0 (grp b), 7 = big1 (grp b+64 / wp)
  int dstA = -1, xoffA = 0, strideA = 512;
  bool reluA = false;
  float biasA = 0.f;
  const float* preAPtr = nullptr;
  const float* wARow = nullptr;
  if (lw < 2) {
    int col = b * 8 + g;
    dstA = col; reluA = true; biasA = a.b_ca[col]; preAPtr = a.PAca + col;
    wARow = a.TWca + (size_t)col * 512; xoffA = 0;
  } else if (lw < 4) {
    int col = b * 8 + (g - 8);
    dstA = 512 + col; reluA = true; biasA = a.b_cm[col]; preAPtr = a.PMcm + col;
    wARow = a.TWcm + (size_t)col * 512; xoffA = 512;
  } else if (lw == 4) {
    int sl = g - 16;
    strideA = 100;
    if (sl == 0)                  { dstA = 1124 + r0a;      biasA = a.b_wpa[r0a];      preAPtr = a.PAwpa + r0a;      wARow = a.TWwpa + (size_t)r0a * 512;        xoffA = 0;   }
    else if (sl == 1 && r0a < 36) { dstA = 1124 + r0a + 64; biasA = a.b_wpa[r0a + 64]; preAPtr = a.PAwpa + r0a + 64; wARow = a.TWwpa + (size_t)(r0a + 64) * 512; xoffA = 0;   }
    else if (sl == 2)             { dstA = 1224 + r1m;      biasA = a.b_wpm[r1m];      preAPtr = a.PMwpm + r1m;      wARow = a.TWwpm + (size_t)r1m * 512;        xoffA = 512; }
    else if (sl == 3 && r1m < 36) { dstA = 1224 + r1m + 64; biasA = a.b_wpm[r1m + 64]; preAPtr = a.PMwpm + r1m + 64; wARow = a.TWwpm + (size_t)(r1m + 64) * 512; xoffA = 512; }
  }
  int dstBig = -1;
  float biasBig = 0.f;
  const float* wBigRow = nullptr;
  if (lw == 6) { dstBig = 1024 + b; biasBig = a.b_rp[b]; wBigRow = a.TWrp + (size_t)b * 1536; }
  else if (lw == 7) {
    if (big1_grp)      { dstBig = 1024 + b + 64;   biasBig = a.b_rp[b + 64]; wBigRow = a.TWrp + (size_t)(b + 64) * 1536; }
    else if (big1_wp)  { dstBig = 1324 + (b - 40); biasBig = a.b_wp[b - 40]; wBigRow = a.TWwp + (size_t)(b - 40) * 1536; }
  }
  // owned / wh: group g < 24 owns carry row q = b*24+g (wh row == owned row)
  const bool own = (g < OWNB);
  int ownHsel = 0, ownJ = 0, whXo = 0;
  float biasO = 0.f;
  const float* preOPtr = nullptr;
  const float* whRow = nullptr;
  const float* uRow = nullptr;
  if (own) {
    int q = b * OWNB + g, hsel = q >> 9, j = q & 511;
    ownHsel = hsel; ownJ = j;
    if (hsel == 0)      { biasO = a.b_rh[j];
                          whRow = a.TWh0 + (size_t)j * 512; whXo = 1024;
                          uRow  = a.TWu0 + (size_t)j * 512; }
    else if (hsel == 1) { biasO = a.b_rha[j]; preOPtr = a.PArha + j;
                          whRow = a.TWh1 + (size_t)j * 512; whXo = 0;
                          uRow  = a.TWu1 + (size_t)j * 512; }
    else                { biasO = a.b_rhm[j]; preOPtr = a.PMrhm + j;
                          whRow = a.TWh2 + (size_t)j * 512; whXo = 512;
                          uRow  = a.TWu2 + (size_t)j * 512; }
  }

  // ---- register-pinned weights (time-invariant; loaded once) ----
  float4 wA[8];   // phase-A row slice (waves 0-4 with a job)
  float4 wU[8];   // owned u-row slice
  float4 wWh[8];  // owned wh-row slice
  float4 wB[6];   // big-gate row slice (waves 6/7)
  float  gr[7];   // G memory rows: private to the owning group
  #pragma unroll
  for (int it = 0; it < 8; ++it) wA[it] = wU[it] = wWh[it] = make_float4(0.f, 0.f, 0.f, 0.f);
  #pragma unroll
  for (int it = 0; it < 6; ++it) wB[it] = make_float4(0.f, 0.f, 0.f, 0.f);
  #pragma unroll
  for (int k = 0; k < 7; ++k) gr[k] = 0.f;

  if (wARow) {
    const float4* w4 = (const float4*)wARow;
    #pragma unroll
    for (int it = 0; it < 8; ++it) wA[it] = w4[gl + 16 * it];
  }
  if (own) {
    const float4* u4 = (const float4*)uRow;
    const float4* h4 = (const float4*)whRow;
    #pragma unroll
    for (int it = 0; it < 8; ++it) { wU[it] = u4[gl + 16 * it]; wWh[it] = h4[gl + 16 * it]; }
  }
  if (wBigRow) {
    const float4* w4 = (const float4*)wBigRow;
    #pragma unroll
    for (int it = 0; it < 6; ++it) wB[it] = w4[lane + 64 * it];
  }
  __syncthreads();

  // ---- prologue: software-pipelined per-step scalars (value for t=0) ----
  float preA_c = preAPtr ? preAPtr[0] : 0.f;
  float preO_c = preOPtr ? preOPtr[0] : 0.f;

  // ---------------- time loop ----------------
  float whv = 0.f;
  for (int t = 0; t < a.nT; ++t) {
    const unsigned tagB = (unsigned)t + 1;
    unsigned long long* bc = a.bcast + (size_t)(t & 1) * 1344;

    // ---- poll carry(t): 3 slots/thread ----
    {
      const unsigned long long* cin = a.carryT + (size_t)(t & 1) * 1536;
      int i0 = tid, i1 = tid + 512, i2 = tid + 1024;
      unsigned long long v0 = ald(cin + i0), v1 = ald(cin + i1), v2 = ald(cin + i2);
      while (((unsigned)(v0 >> 32) < tagB) | ((unsigned)(v1 >> 32) < tagB) |
             ((unsigned)(v2 >> 32) < tagB)) {
        __builtin_amdgcn_s_sleep(1);
        v0 = ald(cin + i0); v1 = ald(cin + i1); v2 = ald(cin + i2);
      }
      s_x[i0] = __uint_as_float((unsigned)v0);
      s_x[i1] = __uint_as_float((unsigned)v1);
      s_x[i2] = __uint_as_float((unsigned)v2);
    }
    __syncthreads();   // SYNC0

    // issue NEXT step's prefetches now: they get the whole step to land
    const int tn = (t + 1 < a.nT) ? t + 1 : t;
    float preA_n = preAPtr ? preAPtr[(size_t)tn * strideA] : 0.f;
    float preO_n = preOPtr ? preOPtr[(size_t)tn * 512] : 0.f;

    // ---- phase A: all critical publishes in ONE parallel round ----
    if (dstA >= 0) {
      const float4* x4 = (const float4*)(s_x + xoffA);
      float acc = 0.f;
      #pragma unroll
      for (int it = 0; it < 8; ++it) {
        float4 xv = x4[gl + 16 * it];
        acc += wA[it].x * xv.x + wA[it].y * xv.y + wA[it].z * xv.z + wA[it].w * xv.w;
      }
      float v = rsum16(acc);
      if (!gl) {
        v += preA_c + biasA;
        if (reluA) v = fmaxf(v, 0.f);
        gstTag(bc + dstA, v, tagB);
      }
    } else if (dstBig >= 0) {
      const float4* x4 = (const float4*)s_x;
      float acc = 0.f;
      #pragma unroll
      for (int it = 0; it < 6; ++it) {
        float4 xv = x4[lane + 64 * it];
        acc += wB[it].x * xv.x + wB[it].y * xv.y + wB[it].z * xv.z + wB[it].w * xv.w;
      }
      float v = xrsum(acc);
      if (!lane) gstTag(bc + dstBig, v + biasBig, tagB);
    }
    // wh dots (register weights; off the inter-block critical path)
    if (own) {
      const float4* x4 = (const float4*)(s_x + whXo);
      float acc = 0.f;
      #pragma unroll
      for (int it = 0; it < 8; ++it) {
        float4 xv = x4[gl + 16 * it];
        acc += wWh[it].x * xv.x + wWh[it].y * xv.y + wWh[it].z * xv.z + wWh[it].w * xv.w;
      }
      whv = rsum16(acc);
    }

    // ---- phase B polls: waves 0-3 softmax groups, waves 4-7 gather c ----
    if (lw < 3) {
      int base = 1024 + lw * 100;       // grp / gwpa / gwpm
      const unsigned long long* p1 = bc + base + lane;
      bool two = lane < 36;
      unsigned long long v1 = ald(p1);
      unsigned long long v2 = two ? ald(p1 + 64) : ~0ull;
      while (((unsigned)(v1 >> 32) < tagB) | ((unsigned)(v2 >> 32) < tagB)) {
        __builtin_amdgcn_s_sleep(1);
        v1 = ald(p1); if (two) v2 = ald(p1 + 64);
      }
      float x1 = __uint_as_float((unsigned)v1);
      float x2 = two ? __uint_as_float((unsigned)v2) : -3.0e38f;
      float m = fmaxf(x1, x2);
      #pragma unroll
      for (int o = 32; o; o >>= 1) m = fmaxf(m, __shfl_xor(m, o, 64));
      float e1 = expf(x1 - m);
      float e2 = two ? expf(x2 - m) : 0.f;
      float ss = e1 + e2;
      #pragma unroll
      for (int o = 32; o; o >>= 1) ss += __shfl_xor(ss, o, 64);
      float inv = 1.f / ss;
      float* dst = (lw == 0) ? s_ar : (lw == 1) ? s_awa : s_awm;
      dst[lane] = e1 * inv;
      if (two) dst[64 + lane] = e2 * inv;
    } else if (lw == 3) {
      float x = -3.0e38f;
      if (lane < 3) {
        const unsigned long long* p = bc + 1324 + lane;
        unsigned long long v = ald(p);
        while ((unsigned)(v >> 32) < tagB) { __builtin_amdgcn_s_sleep(1); v = ald(p); }
        x = __uint_as_float((unsigned)v);
      }
      float m = x;
      #pragma unroll
      for (int o = 32; o; o >>= 1) m = fmaxf(m, __shfl_xor(m, o, 64));
      float e = (lane < 3) ? expf(x - m) : 0.f;
      float ss = e;
      #pragma unroll
      for (int o = 32; o; o >>= 1) ss += __shfl_xor(ss, o, 64);
      if (lane < 3) s_aw[lane] = e / ss;
    } else {
      int base = tid - 256;              // 0..255, 4 slots each
      const unsigned long long* p = bc + base;
      unsigned long long v0 = ald(p), v1 = ald(p + 256), v2 = ald(p + 512), v3 = ald(p + 768);
      while (((unsigned)(v0 >> 32) < tagB) | ((unsigned)(v1 >> 32) < tagB) |
             ((unsigned)(v2 >> 32) < tagB) | ((unsigned)(v3 >> 32) < tagB)) {
        __builtin_amdgcn_s_sleep(1);
        v0 = ald(p); v1 = ald(p + 256); v2 = ald(p + 512); v3 = ald(p + 768);
      }
      s_c[base]       = __uint_as_float((unsigned)v0);
      s_c[base + 256] = __uint_as_float((unsigned)v1);
      s_c[base + 512] = __uint_as_float((unsigned)v2);
      s_c[base + 768] = __uint_as_float((unsigned)v3);
    }
    __syncthreads();   // SYNC1

    // ---- owned phase: ONE parallel round, publish h' BEFORE G update ----
    unsigned long long* cout = a.carryT + (size_t)((t + 1) & 1) * 1536;
    if (own) {
      const float aw0 = s_aw[0], aw1 = s_aw[1], aw2 = s_aw[2];
      // dual u-dot from register weights (uA over ca, uM over cm)
      const float4* a4 = (const float4*)s_c;
      const float4* m4 = (const float4*)(s_c + 512);
      float sa = 0.f, sm = 0.f;
      #pragma unroll
      for (int it = 0; it < 8; ++it) {
        float4 av = a4[gl + 16 * it], mv = m4[gl + 16 * it];
        sa += wU[it].x * av.x + wU[it].y * av.y + wU[it].z * av.z + wU[it].w * av.w;
        sm += wU[it].x * mv.x + wU[it].y * mv.y + wU[it].z * mv.z + wU[it].w * mv.w;
      }
      #pragma unroll
      for (int o = 8; o; o >>= 1) { sa += __shfl_xor(sa, o, 64); sm += __shfl_xor(sm, o, 64); }
      const float uA = sa, uM = sm;

      // contrib from register-resident G (pads: s_ar[100..111] == 0)
      float contrib = 0.f;
      #pragma unroll
      for (int k = 0; k < 7; ++k) contrib += s_ar[gl + 16 * k] * gr[k];
      contrib = rsum16(contrib);
      if (!gl) {
        float h = fmaxf(contrib + whv + preO_c + biasO, 0.f);
        if (ownHsel == 0) {
          a.out[(size_t)t * 512 + ownJ] = h;
          gstTag(cout + 1024 + ownJ, h, tagB + 1);
        } else if (ownHsel == 1) {
          gstTag(cout + ownJ, h, tagB + 1);
        } else {
          gstTag(cout + 512 + ownJ, h, tagB + 1);
        }
      }
      // G update (registers; reads s_awa/s_awm — safe until SYNC0(t+1))
      #pragma unroll
      for (int k = 0; k < 7; ++k) {
        int idx = gl + 16 * k;
        gr[k] = aw0 * gr[k] + aw1 * s_awa[idx] * uA + aw2 * s_awm[idx] * uM;
      }
    }
    // NO SYNC2: a wave can only pass the carry poll of step t+1 after every
    // wave (globally, incl. own block) executed its h'-publish, which is
    // program-order after all step-t reads of s_x/s_c/s_ar/s_awa/s_aw;
    // SYNC0(t+1) then fences the deferred G-update reads against phase-B
    // rewrites of s_awa/s_awm.

    // rotate the pipelined prefetch registers
    preA_c = preA_n;
    preO_c = preO_n;
  }
}

// ---------------- host ----------------
extern "C" void kernel_launch(void* const* d_in, const int* in_sizes, int n_in,
                              void* d_out, int out_size, void* d_ws, size_t ws_size,
                              hipStream_t stream) {
  const float* Xa    = (const float*)d_in[0];
  const float* Xm    = (const float*)d_in[1];
  const float* W_ca  = (const float*)d_in[2];  const float* b_ca  = (const float*)d_in[3];
  const float* W_cm  = (const float*)d_in[4];  const float* b_cm  = (const float*)d_in[5];
  const float* W_wp  = (const float*)d_in[6];  const float* b_wp  = (const float*)d_in[7];
  const float* W_wpa = (const float*)d_in[8];  const float* b_wpa = (const float*)d_in[9];
  const float* W_wpm = (const float*)d_in[10]; const float* b_wpm = (const float*)d_in[11];
  const float* W_rp  = (const float*)d_in[12]; const float* b_rp  = (const float*)d_in[13];
  const float* W_rh  = (const float*)d_in[14]; const float* b_rh  = (const float*)d_in[15];
  const float* W_rha = (const float*)d_in[16]; const float* b_rha = (const float*)d_in[17];
  const float* W_rhm = (const float*)d_in[18]; const float* b_rhm = (const float*)d_in[19];

  int nT = out_size / HS;   // 4096
  float* ws = (float*)d_ws;

  initK<<<dim3(64), dim3(256), 0, stream>>>(
      (unsigned long long*)(ws + OFF_CARRY),
      (unsigned long long*)(ws + OFF_BCAST));

  dim3 tb(32, 8);
  auto tg = [](int R, int C) { return dim3((C + 31) / 32, (R + 31) / 32); };
  transK<<<tg(1536, 100), tb, 0, stream>>>(W_rp,                       ws + OFF_TWrp,  1536, 100);
  transK<<<tg(1536, 3),   tb, 0, stream>>>(W_wp,                       ws + OFF_TWwp,  1536, 3);
  transK<<<tg(512, 100),  tb, 0, stream>>>(W_wpa,                      ws + OFF_TWwpa, 512, 100);
  transK<<<tg(512, 100),  tb, 0, stream>>>(W_wpm,                      ws + OFF_TWwpm, 512, 100);
  transK<<<tg(512, 512),  tb, 0, stream>>>(W_ca,                       ws + OFF_TWca,  512, 512);
  transK<<<tg(512, 512),  tb, 0, stream>>>(W_cm,                       ws + OFF_TWcm,  512, 512);
  transK<<<tg(512, 512),  tb, 0, stream>>>(W_rh  + 512 * 512,          ws + OFF_TWh0,  512, 512);
  transK<<<tg(512, 512),  tb, 0, stream>>>(W_rha + (size_t)2560 * 512, ws + OFF_TWh1,  512, 512);
  transK<<<tg(512, 512),  tb, 0, stream>>>(W_rhm + (size_t)2560 * 512, ws + OFF_TWh2,  512, 512);
  transK<<<tg(512, 512),  tb, 0, stream>>>(W_rh,                       ws + OFF_TWu0,  512, 512);
  transK<<<tg(512, 512),  tb, 0, stream>>>(W_rha + (size_t)2048 * 512, ws + OFF_TWu1,  512, 512);
  transK<<<tg(512, 512),  tb, 0, stream>>>(W_rhm + (size_t)2048 * 512, ws + OFF_TWu2,  512, 512);

  int tB = nT / 128;
  gemm128<<<dim3(4, tB), dim3(256), 0, stream>>>(Xa, W_ca + (size_t)512 * 512, ws + OFF_PAca);
  gemm128<<<dim3(4, tB), dim3(256), 0, stream>>>(Xm, W_cm + (size_t)512 * 512, ws + OFF_PMcm);
  gemm128<<<dim3(4, tB), dim3(256), 0, stream>>>(Xa, W_rha,                    ws + OFF_PArha);
  gemm128<<<dim3(4, tB), dim3(256), 0, stream>>>(Xm, W_rhm,                    ws + OFF_PMrhm);
  int tB64 = nT / 64;
  gemmK<<<dim3(2, tB64), dim3(256), 0, stream>>>(Xa, W_wpa + (size_t)512 * 100, ws + OFF_PAwpa, 100);
  gemmK<<<dim3(2, tB64), dim3(256), 0, stream>>>(Xm, W_wpm + (size_t)512 * 100, ws + OFF_PMwpm, 100);

  RArgs a;
  a.TWrp  = ws + OFF_TWrp;  a.TWwp  = ws + OFF_TWwp;
  a.TWwpa = ws + OFF_TWwpa; a.TWwpm = ws + OFF_TWwpm;
  a.TWca  = ws + OFF_TWca;  a.TWcm  = ws + OFF_TWcm;
  a.TWh0  = ws + OFF_TWh0;  a.TWh1  = ws + OFF_TWh1;  a.TWh2 = ws + OFF_TWh2;
  a.TWu0  = ws + OFF_TWu0;  a.TWu1  = ws + OFF_TWu1;  a.TWu2 = ws + OFF_TWu2;
  a.PAca  = ws + OFF_PAca;  a.PMcm  = ws + OFF_PMcm;
  a.PArha = ws + OFF_PArha; a.PMrhm = ws + OFF_PMrhm;
  a.PAwpa = ws + OFF_PAwpa; a.PMwpm = ws + OFF_PMwpm;
  a.b_ca = b_ca; a.b_cm = b_cm; a.b_wp = b_wp; a.b_wpa = b_wpa; a.b_wpm = b_wpm;
  a.b_rp = b_rp; a.b_rh = b_rh; a.b_rha = b_rha; a.b_rhm = b_rhm;
  a.carryT = (unsigned long long*)(ws + OFF_CARRY);
  a.bcast  = (unsigned long long*)(ws + OFF_BCAST);
  a.out    = (float*)d_out;
  a.nT     = nT;

  recurK<<<dim3(GBLK), dim3(TPB), 0, stream>>>(a);
}